// Round 13
// baseline (378.140 us; speedup 1.0000x reference)
//
#include <hip/hip_runtime.h>
#include <math.h>

#define H 128
#define NHD 8
#define DH 16
#define RB 6
#define NBI 2
#define BSG 16
#define LBLK 64
#define KATOM 16
#define NBLKT 1024
#define NA 16384
#define NE 262144
#define EBE 512

__device__ __forceinline__ float fsilu(float v) {
  return v * __builtin_amdgcn_rcpf(1.0f + __expf(-v));
}

// ---------------- bf16 helpers + MFMA ----------------
typedef short v4s __attribute__((ext_vector_type(4)));
typedef float f32x4 __attribute__((ext_vector_type(4)));

__device__ __forceinline__ short f2bf(float f) {
  union { float f; unsigned u; } v; v.f = f;
  unsigned r = v.u + 0x7fffu + ((v.u >> 16) & 1u);   // RNE to bf16
  return (short)(r >> 16);
}

__device__ __forceinline__ float bf2f(short s) {
  union { unsigned u; float f; } v;
  v.u = ((unsigned)(unsigned short)s) << 16;
  return v.f;
}

#if defined(__has_builtin)
#if __has_builtin(__builtin_amdgcn_mfma_f32_16x16x16bf16_1k)
#define HAVE_MFMA16_1K 1
#endif
#endif

#ifdef HAVE_MFMA16_1K
__device__ __forceinline__ f32x4 mfma16(v4s a, v4s b, f32x4 c) {
  return __builtin_amdgcn_mfma_f32_16x16x16bf16_1k(a, b, c, 0, 0, 0);
}
#else
typedef short v8s __attribute__((ext_vector_type(8)));
__device__ __forceinline__ f32x4 mfma16(v4s a, v4s b, f32x4 c) {
  v8s a8 = {a[0], a[1], a[2], a[3], 0, 0, 0, 0};
  v8s b8 = {b[0], b[1], b[2], b[3], 0, 0, 0, 0};
  return __builtin_amdgcn_mfma_f32_16x16x32_bf16(a8, b8, c, 0, 0, 0);
}
#endif

// ---------------- edge sort: histogram ----------------
__global__ __launch_bounds__(256) void k_hist(
    const int* __restrict__ ei, int* __restrict__ cnt)
{
  int e = blockIdx.x * 256 + threadIdx.x;
  atomicAdd(&cnt[ei[e]], 1);
}

// ---------------- edge sort: shuffle scan (2 barriers, 1 block) ----------
__global__ __launch_bounds__(1024) void k_scan(
    const int* __restrict__ cnt, int* __restrict__ off,
    int* __restrict__ cur, float* __restrict__ cntf)
{
  __shared__ int wsum[16];
  int t = threadIdx.x;
  int lane = t & 63, wid = t >> 6;
  int base = t * 16;
  int local[16];
  int s = 0;
  #pragma unroll
  for (int k = 0; k < 16; ++k) {
    local[k] = s;
    int c = cnt[base + k];
    cntf[base + k] = (float)c;
    s += c;
  }
  int tot = s;
  #pragma unroll
  for (int d = 1; d < 64; d <<= 1) {
    int v = __shfl_up(s, d);
    if (lane >= d) s += v;
  }
  if (lane == 63) wsum[wid] = s;
  __syncthreads();
  if (t < 16) {
    int w = wsum[t];
    #pragma unroll
    for (int d = 1; d < 16; d <<= 1) {
      int v = __shfl_up(w, d, 16);
      if (t >= d) w += v;
    }
    wsum[t] = w;
  }
  __syncthreads();
  int offset = (wid ? wsum[wid - 1] : 0) + (s - tot);
  #pragma unroll
  for (int k = 0; k < 16; ++k) {
    int o = offset + local[k];
    off[base + k] = o;
    cur[base + k] = o;
  }
  if (t == 1023) off[NA] = wsum[15];
}

// ---------------- merged: edge scatter+RBF + block-edge CSR ----------------
__global__ __launch_bounds__(256) void k_scatter_b(
    const int* __restrict__ ei, const int* __restrict__ ej,
    const float* __restrict__ coords, const float* __restrict__ freq,
    int* __restrict__ cur, int* __restrict__ ej_s, float* __restrict__ rbf_s,
    const int* __restrict__ bedges, int* __restrict__ blist,
    int* __restrict__ boff, float* __restrict__ ind)
{
  __shared__ int hist[64], offs[65], curs[64];
  int t = threadIdx.x;
  if (blockIdx.x < NE / 256) {
    int e = blockIdx.x * 256 + t;
    int i = ei[e], j = ej[e];
    int pos = atomicAdd(&cur[i], 1);
    ej_s[pos] = j;
    float dx = coords[i*3+0] - coords[j*3+0];
    float dy = coords[i*3+1] - coords[j*3+1];
    float dz = coords[i*3+2] - coords[j*3+2];
    float d = sqrtf(dx*dx + dy*dy + dz*dz);
    float u = fmaxf(d * 0.125f, 1e-3f);
    float u2 = u*u, u4 = u2*u2, u5 = u4*u, u6 = u5*u, u7 = u6*u;
    float env = 1.0f/u - 28.0f*u5 + 48.0f*u6 - 21.0f*u7;
    #pragma unroll
    for (int r = 0; r < RB; ++r)
      rbf_s[(size_t)pos*RB + r] = env * __sinf(freq[r] * u);
    return;
  }
  int b = blockIdx.x - NE / 256;
  if (t < 64) hist[t] = 0;
  __syncthreads();
  for (int e = t; e < EBE; e += 256) atomicAdd(&hist[bedges[(b*EBE + e)*2]], 1);
  __syncthreads();
  if (t == 0) {
    offs[0] = 0;
    for (int k = 0; k < 64; ++k) offs[k+1] = offs[k] + hist[k];
  }
  __syncthreads();
  if (t < 64) curs[t] = offs[t];
  __syncthreads();
  for (int e = t; e < EBE; e += 256) {
    int src = bedges[(b*EBE + e)*2];
    int pos = atomicAdd(&curs[src], 1);
    blist[b*EBE + pos] = e;
  }
  if (t < 65) boff[b*65 + t] = offs[t];
  if (t < 64) ind[b*64 + t] = (hist[t] > 0) ? 1.0f : 0.0f;
}

// ---------------- merged weight prep ----------------------------------------
__global__ __launch_bounds__(256) void k_prep(
    const float* __restrict__ W2base, const float* __restrict__ U1base,
    const float* __restrict__ b2base, float* __restrict__ bvecbase,
    short* __restrict__ wt_u1base,
    const float* __restrict__ inter_w1, const float* __restrict__ upd_w2,
    const float* __restrict__ edge_w1, const float* __restrict__ edge_w2,
    const float* __restrict__ attn_in_w,
    short* __restrict__ wt_pq, short* __restrict__ wt_u2,
    short* __restrict__ wt_e1, short* __restrict__ wt_e2,
    short* __restrict__ wt_in)
{
  int bx = blockIdx.x, tid = threadIdx.x;
  if (bx < 128) {
    int k = bx, y = tid >> 7, c = tid & 127;
    const float* W2 = W2base + (size_t)y * H * H;
    const float* U1 = U1base + (size_t)y * 2 * H * H;
    const float* b2 = b2base + y * H;
    float* bvec = bvecbase + y * H;
    short* wt1 = wt_u1base + (size_t)y * 128 * 256;
    const float* U1b = U1 + 128 * H;
    wt1[c * 256 + k] = f2bf(U1[k * H + c]);
    float s = 0.0f;
    for (int t = 0; t < H; ++t) s += W2[k * H + t] * U1b[t * H + c];
    wt1[c * 256 + 128 + k] = f2bf(s);
    if (k == 0) {
      float sb = 0.0f;
      for (int t = 0; t < H; ++t) sb += b2[t] * U1b[t * H + c];
      bvec[c] = sb;
    }
    return;
  }
  int idx = (bx - 128) * 256 + tid;  // 65536 total
  {
    int k = idx & 127, col = (idx >> 7) & 127, y = (idx >> 14) & 1, b = idx >> 15;
    wt_pq[idx] = f2bf(inter_w1[((size_t)b*262 + y*128 + k)*128 + col]);
  }
  if (idx < 2*128*128) {
    int k = idx & 127, col = (idx >> 7) & 127, b = idx >> 14;
    wt_u2[idx] = f2bf(upd_w2[((size_t)b*128 + k)*128 + col]);
    wt_e1[idx] = f2bf(edge_w1[((size_t)b*128 + k)*128 + col]);
  }
  if (idx < 128*128) {
    int k = idx & 127, col = idx >> 7;
    wt_e2[idx] = f2bf(edge_w2[(size_t)k*128 + col]);
  }
  if (idx < 384*128) {
    int k = idx & 127, col = idx >> 7;
    wt_in[idx] = f2bf(attn_in_w[(size_t)k*384 + col]);
  }
}

// ---------------- per-atom CSR edge pass v4: 2-way edge split + pairing ----
__global__ __launch_bounds__(256) void k_edge_csr(
    const short* __restrict__ P, const short* __restrict__ Q,
    const float* __restrict__ rbf_s, const float* __restrict__ W1c,
    const int* __restrict__ ej_s, const int* __restrict__ off,
    float* __restrict__ Hagg)
{
  __shared__ float w[RB * H];
  __shared__ float accs[4][H];
  for (int idx = threadIdx.x; idx < RB * H; idx += 256) w[idx] = W1c[idx];
  __syncthreads();
  int c4 = threadIdx.x & 31;         // channel quad
  int sp = (threadIdx.x >> 5) & 1;   // edge split
  int sub = threadIdx.x >> 6;        // atom within block (0..3)
  int i = blockIdx.x * 4 + sub;
  int e0 = off[i], e1 = off[i + 1];
  short4 p4 = *(const short4*)&P[(size_t)i * H + c4 * 4];
  float4 pv = { bf2f(p4.x), bf2f(p4.y), bf2f(p4.z), bf2f(p4.w) };
  float4 W0 = *(const float4*)&w[0*H + c4*4];
  float4 W1 = *(const float4*)&w[1*H + c4*4];
  float4 W2 = *(const float4*)&w[2*H + c4*4];
  float4 W3 = *(const float4*)&w[3*H + c4*4];
  float4 W4 = *(const float4*)&w[4*H + c4*4];
  float4 W5 = *(const float4*)&w[5*H + c4*4];
  float4 acc = {0, 0, 0, 0};
  int e = e0 + sp;
  for (; e + 2 < e1; e += 4) {
    int j0 = ej_s[e], j1 = ej_s[e + 2];
    short4 qa = *(const short4*)&Q[(size_t)j0 * H + c4 * 4];
    short4 qb = *(const short4*)&Q[(size_t)j1 * H + c4 * 4];
    const float* ra = &rbf_s[(size_t)e * RB];
    const float* rc = &rbf_s[(size_t)(e + 2) * RB];
    float a0 = ra[0], a1 = ra[1], a2 = ra[2], a3 = ra[3], a4 = ra[4], a5 = ra[5];
    float b0 = rc[0], b1 = rc[1], b2 = rc[2], b3 = rc[3], b4 = rc[4], b5 = rc[5];
    float4 qv0 = { bf2f(qa.x), bf2f(qa.y), bf2f(qa.z), bf2f(qa.w) };
    float4 qv1 = { bf2f(qb.x), bf2f(qb.y), bf2f(qb.z), bf2f(qb.w) };
    float4 v0, v1;
    v0.x = pv.x + qv0.x + a0*W0.x + a1*W1.x + a2*W2.x + a3*W3.x + a4*W4.x + a5*W5.x;
    v0.y = pv.y + qv0.y + a0*W0.y + a1*W1.y + a2*W2.y + a3*W3.y + a4*W4.y + a5*W5.y;
    v0.z = pv.z + qv0.z + a0*W0.z + a1*W1.z + a2*W2.z + a3*W3.z + a4*W4.z + a5*W5.z;
    v0.w = pv.w + qv0.w + a0*W0.w + a1*W1.w + a2*W2.w + a3*W3.w + a4*W4.w + a5*W5.w;
    v1.x = pv.x + qv1.x + b0*W0.x + b1*W1.x + b2*W2.x + b3*W3.x + b4*W4.x + b5*W5.x;
    v1.y = pv.y + qv1.y + b0*W0.y + b1*W1.y + b2*W2.y + b3*W3.y + b4*W4.y + b5*W5.y;
    v1.z = pv.z + qv1.z + b0*W0.z + b1*W1.z + b2*W2.z + b3*W3.z + b4*W4.z + b5*W5.z;
    v1.w = pv.w + qv1.w + b0*W0.w + b1*W1.w + b2*W2.w + b3*W3.w + b4*W4.w + b5*W5.w;
    acc.x += fsilu(v0.x) + fsilu(v1.x);
    acc.y += fsilu(v0.y) + fsilu(v1.y);
    acc.z += fsilu(v0.z) + fsilu(v1.z);
    acc.w += fsilu(v0.w) + fsilu(v1.w);
  }
  if (e < e1) {
    int j = ej_s[e];
    short4 q4 = *(const short4*)&Q[(size_t)j * H + c4 * 4];
    float4 qv = { bf2f(q4.x), bf2f(q4.y), bf2f(q4.z), bf2f(q4.w) };
    const float* rb = &rbf_s[(size_t)e * RB];
    float r0 = rb[0], r1 = rb[1], r2 = rb[2], r3 = rb[3], r4 = rb[4], r5 = rb[5];
    float4 v;
    v.x = pv.x + qv.x + r0*W0.x + r1*W1.x + r2*W2.x + r3*W3.x + r4*W4.x + r5*W5.x;
    v.y = pv.y + qv.y + r0*W0.y + r1*W1.y + r2*W2.y + r3*W3.y + r4*W4.y + r5*W5.y;
    v.z = pv.z + qv.z + r0*W0.z + r1*W1.z + r2*W2.z + r3*W3.z + r4*W4.z + r5*W5.z;
    v.w = pv.w + qv.w + r0*W0.w + r1*W1.w + r2*W2.w + r3*W3.w + r4*W4.w + r5*W5.w;
    acc.x += fsilu(v.x); acc.y += fsilu(v.y);
    acc.z += fsilu(v.z); acc.w += fsilu(v.w);
  }
  if (sp == 1) *(float4*)&accs[sub][c4*4] = acc;
  __syncthreads();
  if (sp == 0) {
    float4 o = *(const float4*)&accs[sub][c4*4];
    o.x += acc.x; o.y += acc.y; o.z += acc.z; o.w += acc.w;
    *(float4*)&Hagg[(size_t)i * H + c4 * 4] = o;
  }
}

// ---------------- fused embedding + MFMA P/Q projection (b=0) ----------
__global__ __launch_bounds__(256) void k_embed_pq(
    const int* __restrict__ A, const int* __restrict__ apos,
    const int* __restrict__ btypes,
    const float* __restrict__ emb_atom, const float* __restrict__ emb_pos,
    const float* __restrict__ emb_block,
    const short* __restrict__ WtPQ, const float* __restrict__ b1,
    float* __restrict__ x, short* __restrict__ P, short* __restrict__ Q)
{
  __shared__ short As[64][136];
  __shared__ short Ws[128][72];
  int tid = threadIdx.x;
  int m0 = blockIdx.x * 64;
  int y = blockIdx.y;
  const short* Wt = WtPQ + (size_t)y * 128 * 128;
  short* C = y ? Q : P;
  for (int idx = tid; idx < 64*32; idx += 256) {
    int r = idx >> 5, c4 = idx & 31;
    int row = m0 + r;
    int an = A[row], ap = apos[row], bt = btypes[row >> 4];
    float4 va = *(const float4*)&emb_atom[(size_t)an*H + c4*4];
    float4 vp = *(const float4*)&emb_pos[(size_t)ap*H + c4*4];
    float4 vb = *(const float4*)&emb_block[(size_t)bt*H + c4*4];
    float4 v = { va.x+vp.x+vb.x, va.y+vp.y+vb.y, va.z+vp.z+vb.z, va.w+vp.w+vb.w };
    if (y == 0) *(float4*)&x[(size_t)row*H + c4*4] = v;
    short4 s4 = { f2bf(v.x), f2bf(v.y), f2bf(v.z), f2bf(v.w) };
    *(short4*)&As[r][c4*4] = s4;
  }
  int lane = tid & 63, wv = tid >> 6;
  int c = lane & 15, g = lane >> 4;
  int rowb = wv * 16;
  f32x4 acc[8];
  #pragma unroll
  for (int t = 0; t < 8; ++t) acc[t] = (f32x4){0,0,0,0};
  for (int kc = 0; kc < 2; ++kc) {
    __syncthreads();
    {
      int col = tid >> 1, hh = (tid & 1) * 32;
      const int4* src = (const int4*)&Wt[col*128 + kc*64 + hh];
      int4 a0 = src[0], a1 = src[1], a2 = src[2], a3 = src[3];
      *(int4*)&Ws[col][hh] = a0;      *(int4*)&Ws[col][hh+8] = a1;
      *(int4*)&Ws[col][hh+16] = a2;   *(int4*)&Ws[col][hh+24] = a3;
    }
    __syncthreads();
    #pragma unroll
    for (int ks = 0; ks < 4; ++ks) {
      v4s a = *(const v4s*)&As[rowb + c][kc*64 + ks*16 + g*4];
      #pragma unroll
      for (int ct = 0; ct < 8; ++ct) {
        v4s bf = *(const v4s*)&Ws[ct*16 + c][ks*16 + g*4];
        acc[ct] = mfma16(a, bf, acc[ct]);
      }
    }
  }
  #pragma unroll
  for (int ct = 0; ct < 8; ++ct) {
    int col = ct*16 + c;
    float bb = y ? 0.0f : b1[col];
    #pragma unroll
    for (int r = 0; r < 4; ++r) {
      int row = m0 + rowb + g*4 + r;
      C[(size_t)row*H + col] = f2bf(acc[ct][r] + bb);
    }
  }
}

// ---------------- MFMA projection: C(bf16) = A @ W (+bias if y==0) ----------
__global__ __launch_bounds__(256) void k_pq_mfma(
    const float* __restrict__ x, const short* __restrict__ WtPQ,
    const float* __restrict__ b1,
    short* __restrict__ P, short* __restrict__ Q)
{
  __shared__ short As[64][136];
  __shared__ short Ws[128][72];
  int tid = threadIdx.x;
  int m0 = blockIdx.x * 64;
  int y = blockIdx.y;
  const short* Wt = WtPQ + (size_t)y * 128 * 128;
  short* C = y ? Q : P;
  for (int idx = tid; idx < 64*32; idx += 256) {
    int r = idx >> 5, c4 = idx & 31;
    float4 v = *(const float4*)&x[(size_t)(m0 + r)*H + c4*4];
    short4 s4 = { f2bf(v.x), f2bf(v.y), f2bf(v.z), f2bf(v.w) };
    *(short4*)&As[r][c4*4] = s4;
  }
  int lane = tid & 63, wv = tid >> 6;
  int c = lane & 15, g = lane >> 4;
  int rowb = wv * 16;
  f32x4 acc[8];
  #pragma unroll
  for (int t = 0; t < 8; ++t) acc[t] = (f32x4){0,0,0,0};
  for (int kc = 0; kc < 2; ++kc) {
    __syncthreads();
    {
      int col = tid >> 1, hh = (tid & 1) * 32;
      const int4* src = (const int4*)&Wt[col*128 + kc*64 + hh];
      int4 a0 = src[0], a1 = src[1], a2 = src[2], a3 = src[3];
      *(int4*)&Ws[col][hh] = a0;      *(int4*)&Ws[col][hh+8] = a1;
      *(int4*)&Ws[col][hh+16] = a2;   *(int4*)&Ws[col][hh+24] = a3;
    }
    __syncthreads();
    #pragma unroll
    for (int ks = 0; ks < 4; ++ks) {
      v4s a = *(const v4s*)&As[rowb + c][kc*64 + ks*16 + g*4];
      #pragma unroll
      for (int ct = 0; ct < 8; ++ct) {
        v4s bf = *(const v4s*)&Ws[ct*16 + c][ks*16 + g*4];
        acc[ct] = mfma16(a, bf, acc[ct]);
      }
    }
  }
  #pragma unroll
  for (int ct = 0; ct < 8; ++ct) {
    int col = ct*16 + c;
    float bb = y ? 0.0f : b1[col];
    #pragma unroll
    for (int r = 0; r < 4; ++r) {
      int row = m0 + rowb + g*4 + r;
      C[(size_t)row*H + col] = f2bf(acc[ct][r] + bb);
    }
  }
}

// ---------------- MFMA chained update v4: 32-row tile, 1024 thr / 16 waves,
//   grid NA/32 = 512 blocks -> 2 blocks/CU (2048 thr/CU = max occupancy).
//   Each wave = 16 rows x 16 cols (acc[1]). Bit-identical math. --------------
__global__ __launch_bounds__(1024) void k_upd_mfma(
    const float* __restrict__ x, const float* __restrict__ Hagg,
    const short* __restrict__ Wt1,   // [128 col][256 k] bf16
    const float* __restrict__ b1, const float* __restrict__ bvec,
    const float* __restrict__ cntf,
    const short* __restrict__ Wt2,   // [128 col][128 k] bf16
    const float* __restrict__ b2,
    float* __restrict__ xout, float* __restrict__ blocksOut,
    const short* __restrict__ WtN,   // next-block P/Q weights (or null)
    const float* __restrict__ b1N,
    short* __restrict__ Pn, short* __restrict__ Qn)
{
  __shared__ short As[32][264];   // 16.9 KB
  __shared__ short Ws[128][72];   // 18.4 KB
  __shared__ short Us[32][136];   //  8.7 KB  -> 44 KB total, 2 blocks/CU
  int tid = threadIdx.x;
  int m0 = blockIdx.x * 32;
  for (int idx = tid; idx < 32*64; idx += 1024) {
    int r = idx >> 6, c4 = idx & 63;
    const float* src = (c4 < 32) ? &x[(size_t)(m0 + r)*H + c4*4]
                                 : &Hagg[(size_t)(m0 + r)*H + (c4-32)*4];
    float4 v = *(const float4*)src;
    short4 s4 = { f2bf(v.x), f2bf(v.y), f2bf(v.z), f2bf(v.w) };
    *(short4*)&As[r][c4*4] = s4;
  }
  int lane = tid & 63, wv = tid >> 6;       // 16 waves
  int c = lane & 15, g = lane >> 4;
  int rowb = (wv & 1) * 16;                 // row half (0..1)
  int cb = (wv >> 1) * 16;                  // col group (0..7)
  f32x4 acc0 = (f32x4){0,0,0,0};
  // GEMM1: K=256 in 4 chunks of 64
  for (int kc = 0; kc < 4; ++kc) {
    __syncthreads();
    {
      int col = tid >> 3, hh = (tid & 7) * 8;
      *(int4*)&Ws[col][hh] = *(const int4*)&Wt1[col*256 + kc*64 + hh];
    }
    __syncthreads();
    #pragma unroll
    for (int ks = 0; ks < 4; ++ks) {
      v4s a = *(const v4s*)&As[rowb + c][kc*64 + ks*16 + g*4];
      v4s bf = *(const v4s*)&Ws[cb + c][ks*16 + g*4];
      acc0 = mfma16(a, bf, acc0);
    }
  }
  // epilogue 1: U = silu(acc + b1 + bvec*cnt) -> bf16 Us
  {
    int col = cb + c;
    float bb = b1[col], bv = bvec[col];
    #pragma unroll
    for (int r = 0; r < 4; ++r) {
      float cr = cntf[m0 + rowb + g*4 + r];
      float v = acc0[r] + bb + bv * cr;
      Us[rowb + g*4 + r][col] = f2bf(fsilu(v));
      acc0[r] = 0.0f;
    }
  }
  // GEMM2: K=128 in 2 chunks of 64 (barrier at loop top covers Us visibility)
  for (int kc = 0; kc < 2; ++kc) {
    __syncthreads();
    {
      int col = tid >> 3, hh = (tid & 7) * 8;
      *(int4*)&Ws[col][hh] = *(const int4*)&Wt2[col*128 + kc*64 + hh];
    }
    __syncthreads();
    #pragma unroll
    for (int ks = 0; ks < 4; ++ks) {
      v4s a = *(const v4s*)&Us[rowb + c][kc*64 + ks*16 + g*4];
      v4s bf = *(const v4s*)&Ws[cb + c][ks*16 + g*4];
      acc0 = mfma16(a, bf, acc0);
    }
  }
  // final epilogue: xout = acc + b2 + x; optional block-mean; optional stash
  {
    int col = cb + c;
    float bb = b2[col];
    float bs = 0.0f;
    #pragma unroll
    for (int r = 0; r < 4; ++r) {
      int row = m0 + rowb + g*4 + r;
      float v = acc0[r] + bb + x[(size_t)row*H + col];
      xout[(size_t)row*H + col] = v;
      if (WtN) As[rowb + g*4 + r][col] = f2bf(v);
      bs += v;
    }
    if (blocksOut) {
      bs += __shfl_xor(bs, 16);
      bs += __shfl_xor(bs, 32);
      if (g == 0)
        blocksOut[(size_t)(m0/KATOM + (wv & 1))*H + col] = bs * (1.0f / KATOM);
    }
  }
  // fused next-block P/Q projection from the LDS-resident new-x tile
  if (WtN) {
    __syncthreads();
    for (int y = 0; y < 2; ++y) {
      const short* Wt = WtN + (size_t)y * 128 * 128;
      acc0 = (f32x4){0,0,0,0};
      for (int kc = 0; kc < 2; ++kc) {
        __syncthreads();
        {
          int col = tid >> 3, hh = (tid & 7) * 8;
          *(int4*)&Ws[col][hh] = *(const int4*)&Wt[col*128 + kc*64 + hh];
        }
        __syncthreads();
        #pragma unroll
        for (int ks = 0; ks < 4; ++ks) {
          v4s a = *(const v4s*)&As[rowb + c][kc*64 + ks*16 + g*4];
          v4s bf = *(const v4s*)&Ws[cb + c][ks*16 + g*4];
          acc0 = mfma16(a, bf, acc0);
        }
      }
      short* C = y ? Qn : Pn;
      int col = cb + c;
      float bb = y ? 0.0f : b1N[col];
      #pragma unroll
      for (int r = 0; r < 4; ++r) {
        int row = m0 + rowb + g*4 + r;
        C[(size_t)row*H + col] = f2bf(acc0[r] + bb);
      }
    }
  }
}

// ---------------- MFMA block-edge prep: gather+relu -> @edge_w2+b2e ->
//                  @attn_in_w+bin -> Qe/Ke/Ve (bf16 split layout) ------------
__global__ __launch_bounds__(256) void k_eprep_mfma(
    const short* __restrict__ Pb, const short* __restrict__ Qb,
    const int* __restrict__ bedges,
    const short* __restrict__ Wt2e, const float* __restrict__ b2e,
    const short* __restrict__ WtIn, const float* __restrict__ bin,
    short* __restrict__ Qe, short* __restrict__ Ke, short* __restrict__ Ve)
{
  __shared__ short As[64][136];
  __shared__ short Ws[128][72];
  __shared__ short Us[64][136];
  int tid = threadIdx.x;
  int m0 = blockIdx.x * 64;
  for (int idx = tid; idx < 64*32; idx += 256) {
    int r = idx >> 5, c4 = idx & 31;
    int row = m0 + r;
    int g = row >> 9;
    int src = bedges[row*2], dst = bedges[row*2 + 1];
    short4 p4 = *(const short4*)&Pb[(size_t)(g*LBLK + src)*H + c4*4];
    short4 q4 = *(const short4*)&Qb[(size_t)(g*LBLK + dst)*H + c4*4];
    short4 s4;
    s4.x = f2bf(fmaxf(bf2f(p4.x) + bf2f(q4.x), 0.0f));
    s4.y = f2bf(fmaxf(bf2f(p4.y) + bf2f(q4.y), 0.0f));
    s4.z = f2bf(fmaxf(bf2f(p4.z) + bf2f(q4.z), 0.0f));
    s4.w = f2bf(fmaxf(bf2f(p4.w) + bf2f(q4.w), 0.0f));
    *(short4*)&As[r][c4*4] = s4;
  }
  int lane = tid & 63, wv = tid >> 6;
  int c = lane & 15, g = lane >> 4;
  int rowb = wv * 16;
  f32x4 acc[8];
  #pragma unroll
  for (int t = 0; t < 8; ++t) acc[t] = (f32x4){0,0,0,0};
  for (int kc = 0; kc < 2; ++kc) {
    __syncthreads();
    {
      int col = tid >> 1, hh = (tid & 1) * 32;
      const int4* src = (const int4*)&Wt2e[col*128 + kc*64 + hh];
      int4 a0 = src[0], a1 = src[1], a2 = src[2], a3 = src[3];
      *(int4*)&Ws[col][hh] = a0;      *(int4*)&Ws[col][hh+8] = a1;
      *(int4*)&Ws[col][hh+16] = a2;   *(int4*)&Ws[col][hh+24] = a3;
    }
    __syncthreads();
    #pragma unroll
    for (int ks = 0; ks < 4; ++ks) {
      v4s a = *(const v4s*)&As[rowb + c][kc*64 + ks*16 + g*4];
      #pragma unroll
      for (int ct = 0; ct < 8; ++ct) {
        v4s bf = *(const v4s*)&Ws[ct*16 + c][ks*16 + g*4];
        acc[ct] = mfma16(a, bf, acc[ct]);
      }
    }
  }
  #pragma unroll
  for (int ct = 0; ct < 8; ++ct) {
    int col = ct*16 + c;
    float bb = b2e[col];
    #pragma unroll
    for (int r = 0; r < 4; ++r) {
      Us[rowb + g*4 + r][col] = f2bf(acc[ct][r] + bb);
      acc[ct][r] = 0.0f;
    }
  }
  for (int cc = 0; cc < 3; ++cc) {
    for (int kc = 0; kc < 2; ++kc) {
      __syncthreads();
      {
        int col = tid >> 1, hh = (tid & 1) * 32;
        const int4* src = (const int4*)&WtIn[(size_t)(cc*128 + col)*128 + kc*64 + hh];
        int4 a0 = src[0], a1 = src[1], a2 = src[2], a3 = src[3];
        *(int4*)&Ws[col][hh] = a0;      *(int4*)&Ws[col][hh+8] = a1;
        *(int4*)&Ws[col][hh+16] = a2;   *(int4*)&Ws[col][hh+24] = a3;
      }
      __syncthreads();
      #pragma unroll
      for (int ks = 0; ks < 4; ++ks) {
        v4s a = *(const v4s*)&Us[rowb + c][kc*64 + ks*16 + g*4];
        #pragma unroll
        for (int ct = 0; ct < 8; ++ct) {
          v4s bf = *(const v4s*)&Ws[ct*16 + c][ks*16 + g*4];
          acc[ct] = mfma16(a, bf, acc[ct]);
        }
      }
    }
    #pragma unroll
    for (int ct = 0; ct < 8; ++ct) {
      int col = ct*16 + c;
      float bb = bin[cc*128 + col];
      #pragma unroll
      for (int r = 0; r < 4; ++r) {
        int row = m0 + rowb + g*4 + r;
        short val = f2bf(acc[ct][r] + bb);
        if (cc == 0) {
          Qe[(size_t)row*H + col] = val;
        } else {
          // head-major: [graph*8 + h][s][d]
          size_t o = (((size_t)((row >> 9) * NHD + (col >> 4))) * EBE
                      + (row & 511)) * DH + (col & 15);
          ((cc == 1) ? Ke : Ve)[o] = val;
        }
        acc[ct][r] = 0.0f;
      }
    }
  }
}

// ---------------- fused block tail (y-split over qkv chunks) ----------------
__global__ __launch_bounds__(256) void k_bprep(
    const float* __restrict__ bsum, const float* __restrict__ Wout,
    const float* __restrict__ bout, const float* __restrict__ ind,
    const float* __restrict__ blocks,
    const float* __restrict__ Win, const float* __restrict__ bin,
    float* __restrict__ qkv)
{
  __shared__ float As[32][128];
  __shared__ float Ws[16][128];
  __shared__ float Us[32][128];
  int tid = threadIdx.x;
  int m0 = blockIdx.x * 32;
  int chunk = blockIdx.y;
  for (int idx = tid; idx < 32*32; idx += 256) {
    int r = idx >> 5, k4 = idx & 31;
    *(float4*)&As[r][k4*4] = *(const float4*)&bsum[(size_t)(m0 + r)*H + k4*4];
  }
  int rr = tid >> 5;
  int cq = tid & 31;
  float acc[4][4] = {};
  for (int kk0 = 0; kk0 < 128; kk0 += 16) {
    __syncthreads();
    for (int idx = tid; idx < 16*32; idx += 256) {
      int kr = idx >> 5, c4 = idx & 31;
      *(float4*)&Ws[kr][c4*4] = *(const float4*)&Wout[(size_t)(kk0 + kr)*H + c4*4];
    }
    __syncthreads();
    #pragma unroll
    for (int k4 = 0; k4 < 4; ++k4) {
      float4 w0 = *(const float4*)&Ws[k4*4+0][cq*4];
      float4 w1 = *(const float4*)&Ws[k4*4+1][cq*4];
      float4 w2 = *(const float4*)&Ws[k4*4+2][cq*4];
      float4 w3 = *(const float4*)&Ws[k4*4+3][cq*4];
      #pragma unroll
      for (int i = 0; i < 4; ++i) {
        float4 a = *(const float4*)&As[rr + 8*i][kk0 + k4*4];
        acc[i][0] += a.x*w0.x + a.y*w1.x + a.z*w2.x + a.w*w3.x;
        acc[i][1] += a.x*w0.y + a.y*w1.y + a.z*w2.y + a.w*w3.y;
        acc[i][2] += a.x*w0.z + a.y*w1.z + a.z*w2.z + a.w*w3.z;
        acc[i][3] += a.x*w0.w + a.y*w1.w + a.z*w2.w + a.w*w3.w;
      }
    }
  }
  #pragma unroll
  for (int i = 0; i < 4; ++i) {
    int m = m0 + rr + 8*i;
    float bs = ind[m];
    float4 u;
    float* pu = &u.x;
    #pragma unroll
    for (int j = 0; j < 4; ++j) {
      int c = cq*4 + j;
      pu[j] = acc[i][j] + bout[c] * bs + blocks[(size_t)m*H + c];
    }
    *(float4*)&Us[rr + 8*i][cq*4] = u;
    acc[i][0] = 0.0f; acc[i][1] = 0.0f; acc[i][2] = 0.0f; acc[i][3] = 0.0f;
  }
  for (int kk0 = 0; kk0 < 128; kk0 += 16) {
    __syncthreads();
    for (int idx = tid; idx < 16*32; idx += 256) {
      int kr = idx >> 5, c4 = idx & 31;
      *(float4*)&Ws[kr][c4*4] =
          *(const float4*)&Win[(size_t)(kk0 + kr)*384 + chunk*128 + c4*4];
    }
    __syncthreads();
    #pragma unroll
    for (int k4 = 0; k4 < 4; ++k4) {
      float4 w0 = *(const float4*)&Ws[k4*4+0][cq*4];
      float4 w1 = *(const float4*)&Ws[k4*4+1][cq*4];
      float4 w2 = *(const float4*)&Ws[k4*4+2][cq*4];
      float4 w3 = *(const float4*)&Ws[k4*4+3][cq*4];
      #pragma unroll
      for (int i = 0; i < 4; ++i) {
        float4 a = *(const float4*)&Us[rr + 8*i][kk0 + k4*4];
        acc[i][0] += a.x*w0.x + a.y*w1.x + a.z*w2.x + a.w*w3.x;
        acc[i][1] += a.x*w0.y + a.y*w1.y + a.z*w2.y + a.w*w3.y;
        acc[i][2] += a.x*w0.z + a.y*w1.z + a.z*w2.z + a.w*w3.z;
        acc[i][3] += a.x*w0.w + a.y*w1.w + a.z*w2.w + a.w*w3.w;
      }
    }
  }
  #pragma unroll
  for (int i = 0; i < 4; ++i) {
    int m = m0 + rr + 8*i;
    float4 out;
    float* po = &out.x;
    #pragma unroll
    for (int j = 0; j < 4; ++j)
      po[j] = acc[i][j] + bin[chunk*128 + cq*4 + j];
    *(float4*)&qkv[(size_t)m*384 + chunk*128 + cq*4] = out;
  }
}

// ---------------- MFMA bf16 flash attention (split bf16 Qe/Ke/Ve) -----------
__global__ __launch_bounds__(256) void k_eattn(
    const short* __restrict__ Qe, const short* __restrict__ Ke,
    const short* __restrict__ Ve, float* __restrict__ ea)
{
  constexpr int S = EBE;
  constexpr int NR = BSG * NHD * S;
  __shared__ short Ks[S * DH];
  __shared__ short Vt[DH * (S + 4)];
  int rb = blockIdx.x & 3;
  int bh = blockIdx.x >> 2;
  int b = bh >> 3, h = bh & 7;
  int tid = threadIdx.x;
  const short* kb = Ke + (size_t)bh * S * DH;
  const short* vb = Ve + (size_t)bh * S * DH;
  for (int t = tid; t < S * DH / 8; t += 256)
    ((int4*)Ks)[t] = ((const int4*)kb)[t];
  for (int t = tid; t < S * 2; t += 256) {
    int j = t >> 1, half = t & 1;
    int4 v8 = ((const int4*)vb)[t];
    short vs[8]; *(int4*)vs = v8;
    #pragma unroll
    for (int k = 0; k < 8; ++k)
      Vt[(half*8 + k) * (S + 4) + j] = vs[k];
  }
  __syncthreads();
  int lane = tid & 63, wv = tid >> 6;
  int q = lane & 15;
  int g = lane >> 4;
  for (int qs = 0; qs < 2; ++qs) {
    int row = rb * 128 + qs * 64 + wv * 16 + q;
    v4s qf = *(const v4s*)&Qe[((size_t)b * S + row) * H + h * DH + g * 4];
    f32x4 zero = {0.f, 0.f, 0.f, 0.f};
    f32x4 o = zero;
    float m = -1e30f, lsum = 0.0f;
    for (int t = 0; t < S / 16; ++t) {
      v4s ak = *(const v4s*)&Ks[(t * 16 + q) * DH + g * 4];
      f32x4 st = mfma16(ak, qf, zero);
      float tm = fmaxf(fmaxf(st[0], st[1]), fmaxf(st[2], st[3]));
      tm = fmaxf(tm, __shfl_xor(tm, 16));
      tm = fmaxf(tm, __shfl_xor(tm, 32));
      float mn = fmaxf(m, tm);
      float corr = __expf((m - mn) * 0.25f);
      m = mn;
      float p0 = __expf((st[0] - mn) * 0.25f);
      float p1 = __expf((st[1] - mn) * 0.25f);
      float p2 = __expf((st[2] - mn) * 0.25f);
      float p3 = __expf((st[3] - mn) * 0.25f);
      lsum = lsum * corr + ((p0 + p1) + (p2 + p3));
      o[0] *= corr; o[1] *= corr; o[2] *= corr; o[3] *= corr;
      v4s pb = { f2bf(p0), f2bf(p1), f2bf(p2), f2bf(p3) };
      v4s av = *(const v4s*)&Vt[q * (S + 4) + t * 16 + g * 4];
      o = mfma16(av, pb, o);
    }
    float lt = lsum + __shfl_xor(lsum, 16);
    lt += __shfl_xor(lt, 32);
    float inv = 1.0f / lt;
    float4 outv = { o[0]*inv, o[1]*inv, o[2]*inv, o[3]*inv };
    ((float4*)ea)[(size_t)g * NR + (size_t)bh * S + row] = outv;
  }
}

// gather ea rows per (block, channel) via block-edge CSR; divide by cnt
__global__ __launch_bounds__(256) void k_bsum_gather(
    const float* __restrict__ ea, const int* __restrict__ blist,
    const int* __restrict__ boff, float* __restrict__ bsum)
{
  constexpr int NR = BSG * NHD * EBE;
  int idx = blockIdx.x * 256 + threadIdx.x;
  int i = idx >> 5, c4 = idx & 31;
  int b = i >> 6, blk = i & 63;
  int h = c4 >> 2, d4 = c4 & 3;
  int e0 = boff[b*65 + blk], e1 = boff[b*65 + blk + 1];
  const float4* ea4 = (const float4*)ea;
  size_t basein = (size_t)d4 * NR + (size_t)(b*NHD + h) * EBE;
  float4 s = {0, 0, 0, 0};
  for (int e = e0; e < e1; ++e) {
    int srow = blist[b*EBE + e];
    float4 v = ea4[basein + srow];
    s.x += v.x; s.y += v.y; s.z += v.z; s.w += v.w;
  }
  float cnt = (float)(e1 - e0);
  float sc = (cnt > 0.0f) ? (1.0f / cnt) : 0.0f;
  float4 o = {s.x*sc, s.y*sc, s.z*sc, s.w*sc};
  *(float4*)&bsum[(size_t)i*H + c4*4] = o;
}

// ---------------- block self-attention v2: one block per (graph, head) ------
__global__ __launch_bounds__(64) void k_attnS(
    const float* __restrict__ qkv, float* __restrict__ m2)
{
  __shared__ float Ks[LBLK][DH];
  __shared__ float Vs[LBLK][DH];
  __shared__ float red[LBLK][DH + 1];
  int b = blockIdx.x >> 3, h = blockIdx.x & 7;
  int tid = threadIdx.x;
  const float* base = qkv + (size_t)b * LBLK * 384;
  for (int t = tid; t < 256; t += 64) {
    int j = t >> 2, d4 = t & 3;
    *(float4*)&Ks[j][d4*4] = *(const float4*)(base + (size_t)j*384 + 128 + h*DH + d4*4);
    *(float4*)&Vs[j][d4*4] = *(const float4*)(base + (size_t)j*384 + 256 + h*DH + d4*4);
  }
  __syncthreads();
  int s = tid;
  const float4* qp = (const float4*)(base + (size_t)s * 384 + h * DH);
  float4 q0 = qp[0], q1 = qp[1], q2 = qp[2], q3 = qp[3];
  float m = -1e30f, l = 0.0f;
  float4 o0 = {0,0,0,0}, o1 = {0,0,0,0}, o2 = {0,0,0,0}, o3 = {0,0,0,0};
  for (int c0 = 0; c0 < LBLK; c0 += 32) {
    float scv[32];
    float mc = -1e30f;
    #pragma unroll
    for (int j = 0; j < 32; ++j) {
      float4 k0 = *(const float4*)&Ks[c0+j][0];
      float4 k1 = *(const float4*)&Ks[c0+j][4];
      float4 k2 = *(const float4*)&Ks[c0+j][8];
      float4 k3 = *(const float4*)&Ks[c0+j][12];
      float s0 = q0.x*k0.x + q0.y*k0.y + q0.z*k0.z + q0.w*k0.w;
      float s1 = q1.x*k1.x + q1.y*k1.y + q1.z*k1.z + q1.w*k1.w;
      float s2 = q2.x*k2.x + q2.y*k2.y + q2.z*k2.z + q2.w*k2.w;
      float s3 = q3.x*k3.x + q3.y*k3.y + q3.z*k3.z + q3.w*k3.w;
      float sc = (s0 + s1) + (s2 + s3);
      scv[j] = sc;
      mc = fmaxf(mc, sc);
    }
    float mn = fmaxf(m, mc);
    float corr = __expf((m - mn) * 0.25f);
    l *= corr;
    o0.x *= corr; o0.y *= corr; o0.z *= corr; o0.w *= corr;
    o1.x *= corr; o1.y *= corr; o1.z *= corr; o1.w *= corr;
    o2.x *= corr; o2.y *= corr; o2.z *= corr; o2.w *= corr;
    o3.x *= corr; o3.y *= corr; o3.z *= corr; o3.w *= corr;
    m = mn;
    #pragma unroll
    for (int j = 0; j < 32; ++j) {
      float p = __expf((scv[j] - m) * 0.25f);
      l += p;
      float4 v0 = *(const float4*)&Vs[c0+j][0];
      float4 v1 = *(const float4*)&Vs[c0+j][4];
      float4 v2 = *(const float4*)&Vs[c0+j][8];
      float4 v3 = *(const float4*)&Vs[c0+j][12];
      o0.x += p*v0.x; o0.y += p*v0.y; o0.z += p*v0.z; o0.w += p*v0.w;
      o1.x += p*v1.x; o1.y += p*v1.y; o1.z += p*v1.z; o1.w += p*v1.w;
      o2.x += p*v2.x; o2.y += p*v2.y; o2.z += p*v2.z; o2.w += p*v2.w;
      o3.x += p*v3.x; o3.y += p*v3.y; o3.z += p*v3.z; o3.w += p*v3.w;
    }
  }
  float inv = (1.0f / l) * (1.0f / 64.0f);
  float ov[DH] = {o0.x,o0.y,o0.z,o0.w, o1.x,o1.y,o1.z,o1.w,
                  o2.x,o2.y,o2.z,o2.w, o3.x,o3.y,o3.z,o3.w};
  #pragma unroll
  for (int d = 0; d < DH; ++d) red[s][d] = ov[d] * inv;
  __syncthreads();
  if (s < DH) {
    float acc = 0.0f;
    for (int r = 0; r < LBLK; ++r) acc += red[r][s];
    m2[(size_t)b * H + h * DH + s] = acc;
  }
}

// ---------------- final: out-proj + LN + 3-layer MLP ----------------
__device__ __forceinline__ float bsum128(float v, float* red) {
  int t = threadIdx.x;
  red[t] = v; __syncthreads();
  #pragma unroll
  for (int off = 64; off > 0; off >>= 1) {
    if (t < off) red[t] += red[t + off];
    __syncthreads();
  }
  float s = red[0];
  __syncthreads();
  return s;
}

__global__ __launch_bounds__(128) void k_final(
    const float* __restrict__ m2, const float* __restrict__ out_w,
    const float* __restrict__ out_b, const float* __restrict__ lng,
    const float* __restrict__ lnb, const float* __restrict__ w1,
    const float* __restrict__ b1, const float* __restrict__ w2,
    const float* __restrict__ b2, const float* __restrict__ w3,
    const float* __restrict__ b3, float* __restrict__ out)
{
  __shared__ float buf[128];
  __shared__ float red[128];
  int b = blockIdx.x, t = threadIdx.x;
  buf[t] = m2[b*H + t];
  __syncthreads();
  float g = out_b[t];
  for (int k = 0; k < H; ++k) g += buf[k] * out_w[k*H + t];
  float mu = bsum128(g, red) * (1.0f / H);
  float df = g - mu;
  float var = bsum128(df * df, red) * (1.0f / H);
  float gn = df / sqrtf(var + 1e-5f) * lng[t] + lnb[t];
  __syncthreads();
  buf[t] = gn; __syncthreads();
  float h1 = b1[t];
  for (int k = 0; k < H; ++k) h1 += buf[k] * w1[k*H + t];
  h1 = fmaxf(h1, 0.0f);
  __syncthreads();
  buf[t] = h1; __syncthreads();
  float h2 = b2[t];
  for (int k = 0; k < H; ++k) h2 += buf[k] * w2[k*H + t];
  h2 = fmaxf(h2, 0.0f);
  float tot = bsum128(h2 * w3[t], red);
  if (t == 0) out[b] = tot + b3[0];
}

extern "C" void kernel_launch(void* const* d_in, const int* in_sizes, int n_in,
                              void* d_out, int out_size, void* d_ws, size_t ws_size,
                              hipStream_t stream) {
  (void)in_sizes; (void)n_in; (void)out_size; (void)ws_size;
  const int*   A          = (const int*)d_in[0];
  const int*   apos       = (const int*)d_in[1];
  const int*   btypes     = (const int*)d_in[2];
  const float* coords     = (const float*)d_in[3];
  const int*   edge_index = (const int*)d_in[4];
  const int*   bedges     = (const int*)d_in[5];
  const float* emb_atom   = (const float*)d_in[6];
  const float* emb_pos    = (const float*)d_in[7];
  const float* emb_block  = (const float*)d_in[8];
  const float* rbf_freq   = (const float*)d_in[9];
  const float* inter_w1   = (const float*)d_in[10];
  const float* inter_b1   = (const float*)d_in[11];
  const float* inter_w2   = (const float*)d_in[12];
  const float* inter_b2   = (const float*)d_in[13];
  const float* upd_w1     = (const float*)d_in[14];
  const float* upd_b1     = (const float*)d_in[15];
  const float* upd_w2     = (const float*)d_in[16];
  const float* upd_b2     = (const float*)d_in[17];
  const float* edge_w1    = (const float*)d_in[18];
  const float* edge_b1    = (const float*)d_in[19];
  const float* edge_w2    = (const float*)d_in[20];
  const float* edge_b2    = (const float*)d_in[21];
  const float* attn_in_w  = (const float*)d_in[22];
  const float* attn_in_b  = (const float*)d_in[23];
  const float* attn_out_w = (const float*)d_in[24];
  const float* attn_out_b = (const float*)d_in[25];
  const float* ln_g       = (const float*)d_in[26];
  const float* ln_b       = (const float*)d_in[27];
  const float* fin_w1     = (const float*)d_in[28];
  const float* fin_b1     = (const float*)d_in[29];
  const float* fin_w2     = (const float*)d_in[30];
  const float* fin_b2     = (const float*)d_in[31];
  const float* fin_w3     = (const float*)d_in[32];
  const float* fin_b3     = (const float*)d_in[33];
  float* out = (float*)d_out;

  float* ws = (float*)d_ws;
  float* x      = ws + 0;
  short* P      = (short*)(ws + 2097152);   // NA*H bf16
  short* Q      = (short*)(ws + 4194304);   // NA*H bf16
  float* Hagg   = ws + 6291456;
  float* rbf_s  = ws + 8388608;    // E*6 (sorted RBF)
  float* cntf   = ws + 9961472;    // NA
  float* blocks = ws + 9977856;    // NBLKT*H
  short* Pb     = (short*)(ws + 10108928);  // NBLKT*H bf16
  short* Qb     = (short*)(ws + 10240000);  // NBLKT*H bf16
  // edge-attention split buffers (bf16) + block-level qkv (f32):
  short* Qe     = (short*)(ws + 12468224);            // 16*512*128 bf16
  short* Ke     = (short*)(ws + 12468224 + 524288);   // 16*8*512*16 bf16
  short* Ve     = (short*)(ws + 12468224 + 1048576);  // 16*8*512*16 bf16
  float* qkvB   = ws + 12468224 + 1572864;            // NBLKT*384 f32
  float* bsum   = ws + 15613952;   // NBLKT*H
  float* ind    = ws + 15746048;   // NBLKT
  float* m2     = ws + 15747072;   // BSG*H
  int* blist    = (int*)(ws + 15749120);  // BSG*EBE ints
  int* boff     = (int*)(ws + 15757312);  // BSG*65 ints
  // sort scratch lives in the old-Epre region (dead until attention):
  int* ej_s   = (int*)(ws + 10371072);          // NE ints
  int* off    = (int*)(ws + 10371072 + 262144); // NA+1 ints
  int* cur    = (int*)(ws + 10371072 + 278784); // NA ints
  int* cnt    = (int*)(ws + 10371072 + 295168); // NA ints
  float* bvec = ws + 10371072 + 311552;         // 2 x 128 floats
  // bf16 transposed weights: high region
  short* wt_pq = (short*)(ws + 16777216);            // 2*2*128*128
  short* wt_u1 = (short*)(ws + 16777216 + 32768);    // 2*128*256
  short* wt_u2 = (short*)(ws + 16777216 + 65536);    // 2*128*128
  short* wt_e1 = (short*)(ws + 16777216 + 81920);    // 2*128*128
  short* wt_e2 = (short*)(ws + 16777216 + 98304);    // 128*128
  short* wt_in = (short*)(ws + 16777216 + 106496);   // 384*128
  // edge-attention output (written after sort scratch is dead):
  float* ea     = ws + 10371072;   // 65536*16 floats (old Epre region)

  const int* ei = edge_index;
  const int* ej = edge_index + NE;

  // ---- edge sort (once; reused by both interaction blocks) ----
  (void)hipMemsetAsync(cnt, 0, NA * sizeof(int), stream);
  k_hist<<<NE/256, 256, 0, stream>>>(ei, cnt);
  k_scan<<<1, 1024, 0, stream>>>(cnt, off, cur, cntf);
  // merged: edge scatter+RBF + block-edge CSR
  k_scatter_b<<<NE/256 + BSG, 256, 0, stream>>>(ei, ej, coords, rbf_freq, cur,
                                                ej_s, rbf_s,
                                                bedges, blist, boff, ind);
  // merged weight prep: wprep + all bf16 col-major conversions
  k_prep<<<384, 256, 0, stream>>>(inter_w2, upd_w1, inter_b2, bvec, wt_u1,
                                  inter_w1, upd_w2, edge_w1, edge_w2, attn_in_w,
                                  wt_pq, wt_u2, wt_e1, wt_e2, wt_in);

  // ---- interaction block 0 ----
  k_embed_pq<<<dim3(NA/64, 2), 256, 0, stream>>>(
      A, apos, btypes, emb_atom, emb_pos, emb_block,
      wt_pq, inter_b1, x, P, Q);
  k_edge_csr<<<NA/4, 256, 0, stream>>>(P, Q, rbf_s,
                                       inter_w1 + 256*H, ej_s, off, Hagg);
  // chained update (32-row tile, 512 blocks, 1024 thr) + fused next P/Q
  k_upd_mfma<<<NA/32, 1024, 0, stream>>>(
      x, Hagg, wt_u1, upd_b1, bvec, cntf, wt_u2, upd_b2, x, nullptr,
      wt_pq + (size_t)1*2*128*128, inter_b1 + H, P, Q);

  // ---- interaction block 1 ----
  k_edge_csr<<<NA/4, 256, 0, stream>>>(P, Q, rbf_s,
                                       inter_w1 + (size_t)262*H + 256*H,
                                       ej_s, off, Hagg);
  // chained update (32-row tile) + fused block-mean
  k_upd_mfma<<<NA/32, 1024, 0, stream>>>(
      x, Hagg, wt_u1 + (size_t)128*256, upd_b1 + H, bvec + H, cntf,
      wt_u2 + (size_t)128*128, upd_b2 + H, x, blocks,
      nullptr, nullptr, nullptr, nullptr);

  // MFMA: Pb = blocks@edge_w1a + b (y=0) ; Qb = blocks@edge_w1b (y=1), bf16 out
  k_pq_mfma<<<dim3(NBLKT/64, 2), 256, 0, stream>>>(blocks, wt_e1, edge_b1, Pb, Qb);
  // MFMA: gather+relu -> @edge_w2+b -> @attn_in_w+b -> Qe/Ke/Ve (bf16 split)
  k_eprep_mfma<<<BSG*EBE/64, 256, 0, stream>>>(Pb, Qb, bedges, wt_e2, edge_b2,
                                               wt_in, attn_in_b, Qe, Ke, Ve);
  // MFMA bf16 flash attention (coalesced bf16 staging)
  k_eattn<<<BSG*NHD*(EBE/128), 256, 0, stream>>>(Qe, Ke, Ve, ea);
  k_bsum_gather<<<NBLKT*32/256, 256, 0, stream>>>(ea, blist, boff, bsum);
  // fused tail (y-split, 96 workgroups)
  k_bprep<<<dim3(NBLKT/32, 3), 256, 0, stream>>>(bsum, attn_out_w, attn_out_b,
                                                 ind, blocks, attn_in_w,
                                                 attn_in_b, qkvB);
  // block self-attention: one block per (graph, head), 128 workgroups
  k_attnS<<<BSG*NHD, 64, 0, stream>>>(qkvB, m2);
  k_final<<<BSG, 128, 0, stream>>>(m2, attn_out_w, attn_out_b, ln_g, ln_b,
                                   fin_w1, fin_b1, fin_w2, fin_b2, fin_w3, fin_b3, out);
}

// Round 14
// 373.529 us; speedup vs baseline: 1.0123x; 1.0123x over previous
//
#include <hip/hip_runtime.h>
#include <math.h>

#define H 128
#define NHD 8
#define DH 16
#define RB 6
#define NBI 2
#define BSG 16
#define LBLK 64
#define KATOM 16
#define NBLKT 1024
#define NA 16384
#define NE 262144
#define EBE 512

__device__ __forceinline__ float fsilu(float v) {
  return v * __builtin_amdgcn_rcpf(1.0f + __expf(-v));
}

// ---------------- bf16 helpers + MFMA ----------------
typedef short v4s __attribute__((ext_vector_type(4)));
typedef float f32x4 __attribute__((ext_vector_type(4)));

__device__ __forceinline__ short f2bf(float f) {
  union { float f; unsigned u; } v; v.f = f;
  unsigned r = v.u + 0x7fffu + ((v.u >> 16) & 1u);   // RNE to bf16
  return (short)(r >> 16);
}

__device__ __forceinline__ float bf2f(short s) {
  union { unsigned u; float f; } v;
  v.u = ((unsigned)(unsigned short)s) << 16;
  return v.f;
}

#if defined(__has_builtin)
#if __has_builtin(__builtin_amdgcn_mfma_f32_16x16x16bf16_1k)
#define HAVE_MFMA16_1K 1
#endif
#endif

#ifdef HAVE_MFMA16_1K
__device__ __forceinline__ f32x4 mfma16(v4s a, v4s b, f32x4 c) {
  return __builtin_amdgcn_mfma_f32_16x16x16bf16_1k(a, b, c, 0, 0, 0);
}
#else
typedef short v8s __attribute__((ext_vector_type(8)));
__device__ __forceinline__ f32x4 mfma16(v4s a, v4s b, f32x4 c) {
  v8s a8 = {a[0], a[1], a[2], a[3], 0, 0, 0, 0};
  v8s b8 = {b[0], b[1], b[2], b[3], 0, 0, 0, 0};
  return __builtin_amdgcn_mfma_f32_16x16x32_bf16(a8, b8, c, 0, 0, 0);
}
#endif

// ---------------- edge sort: histogram ----------------
__global__ __launch_bounds__(256) void k_hist(
    const int* __restrict__ ei, int* __restrict__ cnt)
{
  int e = blockIdx.x * 256 + threadIdx.x;
  atomicAdd(&cnt[ei[e]], 1);
}

// ---------------- edge sort: shuffle scan (2 barriers, 1 block) ----------
__global__ __launch_bounds__(1024) void k_scan(
    const int* __restrict__ cnt, int* __restrict__ off,
    int* __restrict__ cur, float* __restrict__ cntf)
{
  __shared__ int wsum[16];
  int t = threadIdx.x;
  int lane = t & 63, wid = t >> 6;
  int base = t * 16;
  int local[16];
  int s = 0;
  #pragma unroll
  for (int k = 0; k < 16; ++k) {
    local[k] = s;
    int c = cnt[base + k];
    cntf[base + k] = (float)c;
    s += c;
  }
  int tot = s;
  #pragma unroll
  for (int d = 1; d < 64; d <<= 1) {
    int v = __shfl_up(s, d);
    if (lane >= d) s += v;
  }
  if (lane == 63) wsum[wid] = s;
  __syncthreads();
  if (t < 16) {
    int w = wsum[t];
    #pragma unroll
    for (int d = 1; d < 16; d <<= 1) {
      int v = __shfl_up(w, d, 16);
      if (t >= d) w += v;
    }
    wsum[t] = w;
  }
  __syncthreads();
  int offset = (wid ? wsum[wid - 1] : 0) + (s - tot);
  #pragma unroll
  for (int k = 0; k < 16; ++k) {
    int o = offset + local[k];
    off[base + k] = o;
    cur[base + k] = o;
  }
  if (t == 1023) off[NA] = wsum[15];
}

// ---------------- merged: edge scatter+RBF + block-edge CSR ----------------
__global__ __launch_bounds__(256) void k_scatter_b(
    const int* __restrict__ ei, const int* __restrict__ ej,
    const float* __restrict__ coords, const float* __restrict__ freq,
    int* __restrict__ cur, int* __restrict__ ej_s, float* __restrict__ rbf_s,
    const int* __restrict__ bedges, int* __restrict__ blist,
    int* __restrict__ boff, float* __restrict__ ind)
{
  __shared__ int hist[64], offs[65], curs[64];
  int t = threadIdx.x;
  if (blockIdx.x < NE / 256) {
    int e = blockIdx.x * 256 + t;
    int i = ei[e], j = ej[e];
    int pos = atomicAdd(&cur[i], 1);
    ej_s[pos] = j;
    float dx = coords[i*3+0] - coords[j*3+0];
    float dy = coords[i*3+1] - coords[j*3+1];
    float dz = coords[i*3+2] - coords[j*3+2];
    float d = sqrtf(dx*dx + dy*dy + dz*dz);
    float u = fmaxf(d * 0.125f, 1e-3f);
    float u2 = u*u, u4 = u2*u2, u5 = u4*u, u6 = u5*u, u7 = u6*u;
    float env = 1.0f/u - 28.0f*u5 + 48.0f*u6 - 21.0f*u7;
    #pragma unroll
    for (int r = 0; r < RB; ++r)
      rbf_s[(size_t)pos*RB + r] = env * __sinf(freq[r] * u);
    return;
  }
  int b = blockIdx.x - NE / 256;
  if (t < 64) hist[t] = 0;
  __syncthreads();
  for (int e = t; e < EBE; e += 256) atomicAdd(&hist[bedges[(b*EBE + e)*2]], 1);
  __syncthreads();
  if (t == 0) {
    offs[0] = 0;
    for (int k = 0; k < 64; ++k) offs[k+1] = offs[k] + hist[k];
  }
  __syncthreads();
  if (t < 64) curs[t] = offs[t];
  __syncthreads();
  for (int e = t; e < EBE; e += 256) {
    int src = bedges[(b*EBE + e)*2];
    int pos = atomicAdd(&curs[src], 1);
    blist[b*EBE + pos] = e;
  }
  if (t < 65) boff[b*65 + t] = offs[t];
  if (t < 64) ind[b*64 + t] = (hist[t] > 0) ? 1.0f : 0.0f;
}

// ---------------- merged weight prep ----------------------------------------
__global__ __launch_bounds__(256) void k_prep(
    const float* __restrict__ W2base, const float* __restrict__ U1base,
    const float* __restrict__ b2base, float* __restrict__ bvecbase,
    short* __restrict__ wt_u1base,
    const float* __restrict__ inter_w1, const float* __restrict__ upd_w2,
    const float* __restrict__ edge_w1, const float* __restrict__ edge_w2,
    const float* __restrict__ attn_in_w,
    short* __restrict__ wt_pq, short* __restrict__ wt_u2,
    short* __restrict__ wt_e1, short* __restrict__ wt_e2,
    short* __restrict__ wt_in)
{
  int bx = blockIdx.x, tid = threadIdx.x;
  if (bx < 128) {
    int k = bx, y = tid >> 7, c = tid & 127;
    const float* W2 = W2base + (size_t)y * H * H;
    const float* U1 = U1base + (size_t)y * 2 * H * H;
    const float* b2 = b2base + y * H;
    float* bvec = bvecbase + y * H;
    short* wt1 = wt_u1base + (size_t)y * 128 * 256;
    const float* U1b = U1 + 128 * H;
    wt1[c * 256 + k] = f2bf(U1[k * H + c]);
    float s = 0.0f;
    for (int t = 0; t < H; ++t) s += W2[k * H + t] * U1b[t * H + c];
    wt1[c * 256 + 128 + k] = f2bf(s);
    if (k == 0) {
      float sb = 0.0f;
      for (int t = 0; t < H; ++t) sb += b2[t] * U1b[t * H + c];
      bvec[c] = sb;
    }
    return;
  }
  int idx = (bx - 128) * 256 + tid;  // 65536 total
  {
    int k = idx & 127, col = (idx >> 7) & 127, y = (idx >> 14) & 1, b = idx >> 15;
    wt_pq[idx] = f2bf(inter_w1[((size_t)b*262 + y*128 + k)*128 + col]);
  }
  if (idx < 2*128*128) {
    int k = idx & 127, col = (idx >> 7) & 127, b = idx >> 14;
    wt_u2[idx] = f2bf(upd_w2[((size_t)b*128 + k)*128 + col]);
    wt_e1[idx] = f2bf(edge_w1[((size_t)b*128 + k)*128 + col]);
  }
  if (idx < 128*128) {
    int k = idx & 127, col = idx >> 7;
    wt_e2[idx] = f2bf(edge_w2[(size_t)k*128 + col]);
  }
  if (idx < 384*128) {
    int k = idx & 127, col = idx >> 7;
    wt_in[idx] = f2bf(attn_in_w[(size_t)k*384 + col]);
  }
}

// ---------------- per-atom CSR edge pass v4: 2-way edge split + pairing ----
__global__ __launch_bounds__(256) void k_edge_csr(
    const short* __restrict__ P, const short* __restrict__ Q,
    const float* __restrict__ rbf_s, const float* __restrict__ W1c,
    const int* __restrict__ ej_s, const int* __restrict__ off,
    float* __restrict__ Hagg)
{
  __shared__ float w[RB * H];
  __shared__ float accs[4][H];
  for (int idx = threadIdx.x; idx < RB * H; idx += 256) w[idx] = W1c[idx];
  __syncthreads();
  int c4 = threadIdx.x & 31;         // channel quad
  int sp = (threadIdx.x >> 5) & 1;   // edge split
  int sub = threadIdx.x >> 6;        // atom within block (0..3)
  int i = blockIdx.x * 4 + sub;
  int e0 = off[i], e1 = off[i + 1];
  short4 p4 = *(const short4*)&P[(size_t)i * H + c4 * 4];
  float4 pv = { bf2f(p4.x), bf2f(p4.y), bf2f(p4.z), bf2f(p4.w) };
  float4 W0 = *(const float4*)&w[0*H + c4*4];
  float4 W1 = *(const float4*)&w[1*H + c4*4];
  float4 W2 = *(const float4*)&w[2*H + c4*4];
  float4 W3 = *(const float4*)&w[3*H + c4*4];
  float4 W4 = *(const float4*)&w[4*H + c4*4];
  float4 W5 = *(const float4*)&w[5*H + c4*4];
  float4 acc = {0, 0, 0, 0};
  int e = e0 + sp;
  for (; e + 2 < e1; e += 4) {
    int j0 = ej_s[e], j1 = ej_s[e + 2];
    short4 qa = *(const short4*)&Q[(size_t)j0 * H + c4 * 4];
    short4 qb = *(const short4*)&Q[(size_t)j1 * H + c4 * 4];
    const float* ra = &rbf_s[(size_t)e * RB];
    const float* rc = &rbf_s[(size_t)(e + 2) * RB];
    float a0 = ra[0], a1 = ra[1], a2 = ra[2], a3 = ra[3], a4 = ra[4], a5 = ra[5];
    float b0 = rc[0], b1 = rc[1], b2 = rc[2], b3 = rc[3], b4 = rc[4], b5 = rc[5];
    float4 qv0 = { bf2f(qa.x), bf2f(qa.y), bf2f(qa.z), bf2f(qa.w) };
    float4 qv1 = { bf2f(qb.x), bf2f(qb.y), bf2f(qb.z), bf2f(qb.w) };
    float4 v0, v1;
    v0.x = pv.x + qv0.x + a0*W0.x + a1*W1.x + a2*W2.x + a3*W3.x + a4*W4.x + a5*W5.x;
    v0.y = pv.y + qv0.y + a0*W0.y + a1*W1.y + a2*W2.y + a3*W3.y + a4*W4.y + a5*W5.y;
    v0.z = pv.z + qv0.z + a0*W0.z + a1*W1.z + a2*W2.z + a3*W3.z + a4*W4.z + a5*W5.z;
    v0.w = pv.w + qv0.w + a0*W0.w + a1*W1.w + a2*W2.w + a3*W3.w + a4*W4.w + a5*W5.w;
    v1.x = pv.x + qv1.x + b0*W0.x + b1*W1.x + b2*W2.x + b3*W3.x + b4*W4.x + b5*W5.x;
    v1.y = pv.y + qv1.y + b0*W0.y + b1*W1.y + b2*W2.y + b3*W3.y + b4*W4.y + b5*W5.y;
    v1.z = pv.z + qv1.z + b0*W0.z + b1*W1.z + b2*W2.z + b3*W3.z + b4*W4.z + b5*W5.z;
    v1.w = pv.w + qv1.w + b0*W0.w + b1*W1.w + b2*W2.w + b3*W3.w + b4*W4.w + b5*W5.w;
    acc.x += fsilu(v0.x) + fsilu(v1.x);
    acc.y += fsilu(v0.y) + fsilu(v1.y);
    acc.z += fsilu(v0.z) + fsilu(v1.z);
    acc.w += fsilu(v0.w) + fsilu(v1.w);
  }
  if (e < e1) {
    int j = ej_s[e];
    short4 q4 = *(const short4*)&Q[(size_t)j * H + c4 * 4];
    float4 qv = { bf2f(q4.x), bf2f(q4.y), bf2f(q4.z), bf2f(q4.w) };
    const float* rb = &rbf_s[(size_t)e * RB];
    float r0 = rb[0], r1 = rb[1], r2 = rb[2], r3 = rb[3], r4 = rb[4], r5 = rb[5];
    float4 v;
    v.x = pv.x + qv.x + r0*W0.x + r1*W1.x + r2*W2.x + r3*W3.x + r4*W4.x + r5*W5.x;
    v.y = pv.y + qv.y + r0*W0.y + r1*W1.y + r2*W2.y + r3*W3.y + r4*W4.y + r5*W5.y;
    v.z = pv.z + qv.z + r0*W0.z + r1*W1.z + r2*W2.z + r3*W3.z + r4*W4.z + r5*W5.z;
    v.w = pv.w + qv.w + r0*W0.w + r1*W1.w + r2*W2.w + r3*W3.w + r4*W4.w + r5*W5.w;
    acc.x += fsilu(v.x); acc.y += fsilu(v.y);
    acc.z += fsilu(v.z); acc.w += fsilu(v.w);
  }
  if (sp == 1) *(float4*)&accs[sub][c4*4] = acc;
  __syncthreads();
  if (sp == 0) {
    float4 o = *(const float4*)&accs[sub][c4*4];
    o.x += acc.x; o.y += acc.y; o.z += acc.z; o.w += acc.w;
    *(float4*)&Hagg[(size_t)i * H + c4 * 4] = o;
  }
}

// ---------------- fused embedding + MFMA P/Q projection (b=0) ----------
__global__ __launch_bounds__(256) void k_embed_pq(
    const int* __restrict__ A, const int* __restrict__ apos,
    const int* __restrict__ btypes,
    const float* __restrict__ emb_atom, const float* __restrict__ emb_pos,
    const float* __restrict__ emb_block,
    const short* __restrict__ WtPQ, const float* __restrict__ b1,
    float* __restrict__ x, short* __restrict__ P, short* __restrict__ Q)
{
  __shared__ short As[64][136];
  __shared__ short Ws[128][72];
  int tid = threadIdx.x;
  int m0 = blockIdx.x * 64;
  int y = blockIdx.y;
  const short* Wt = WtPQ + (size_t)y * 128 * 128;
  short* C = y ? Q : P;
  for (int idx = tid; idx < 64*32; idx += 256) {
    int r = idx >> 5, c4 = idx & 31;
    int row = m0 + r;
    int an = A[row], ap = apos[row], bt = btypes[row >> 4];
    float4 va = *(const float4*)&emb_atom[(size_t)an*H + c4*4];
    float4 vp = *(const float4*)&emb_pos[(size_t)ap*H + c4*4];
    float4 vb = *(const float4*)&emb_block[(size_t)bt*H + c4*4];
    float4 v = { va.x+vp.x+vb.x, va.y+vp.y+vb.y, va.z+vp.z+vb.z, va.w+vp.w+vb.w };
    if (y == 0) *(float4*)&x[(size_t)row*H + c4*4] = v;
    short4 s4 = { f2bf(v.x), f2bf(v.y), f2bf(v.z), f2bf(v.w) };
    *(short4*)&As[r][c4*4] = s4;
  }
  int lane = tid & 63, wv = tid >> 6;
  int c = lane & 15, g = lane >> 4;
  int rowb = wv * 16;
  f32x4 acc[8];
  #pragma unroll
  for (int t = 0; t < 8; ++t) acc[t] = (f32x4){0,0,0,0};
  for (int kc = 0; kc < 2; ++kc) {
    __syncthreads();
    {
      int col = tid >> 1, hh = (tid & 1) * 32;
      const int4* src = (const int4*)&Wt[col*128 + kc*64 + hh];
      int4 a0 = src[0], a1 = src[1], a2 = src[2], a3 = src[3];
      *(int4*)&Ws[col][hh] = a0;      *(int4*)&Ws[col][hh+8] = a1;
      *(int4*)&Ws[col][hh+16] = a2;   *(int4*)&Ws[col][hh+24] = a3;
    }
    __syncthreads();
    #pragma unroll
    for (int ks = 0; ks < 4; ++ks) {
      v4s a = *(const v4s*)&As[rowb + c][kc*64 + ks*16 + g*4];
      #pragma unroll
      for (int ct = 0; ct < 8; ++ct) {
        v4s bf = *(const v4s*)&Ws[ct*16 + c][ks*16 + g*4];
        acc[ct] = mfma16(a, bf, acc[ct]);
      }
    }
  }
  #pragma unroll
  for (int ct = 0; ct < 8; ++ct) {
    int col = ct*16 + c;
    float bb = y ? 0.0f : b1[col];
    #pragma unroll
    for (int r = 0; r < 4; ++r) {
      int row = m0 + rowb + g*4 + r;
      C[(size_t)row*H + col] = f2bf(acc[ct][r] + bb);
    }
  }
}

// ---------------- MFMA projection: C(bf16) = A @ W (+bias if y==0) ----------
__global__ __launch_bounds__(256) void k_pq_mfma(
    const float* __restrict__ x, const short* __restrict__ WtPQ,
    const float* __restrict__ b1,
    short* __restrict__ P, short* __restrict__ Q)
{
  __shared__ short As[64][136];
  __shared__ short Ws[128][72];
  int tid = threadIdx.x;
  int m0 = blockIdx.x * 64;
  int y = blockIdx.y;
  const short* Wt = WtPQ + (size_t)y * 128 * 128;
  short* C = y ? Q : P;
  for (int idx = tid; idx < 64*32; idx += 256) {
    int r = idx >> 5, c4 = idx & 31;
    float4 v = *(const float4*)&x[(size_t)(m0 + r)*H + c4*4];
    short4 s4 = { f2bf(v.x), f2bf(v.y), f2bf(v.z), f2bf(v.w) };
    *(short4*)&As[r][c4*4] = s4;
  }
  int lane = tid & 63, wv = tid >> 6;
  int c = lane & 15, g = lane >> 4;
  int rowb = wv * 16;
  f32x4 acc[8];
  #pragma unroll
  for (int t = 0; t < 8; ++t) acc[t] = (f32x4){0,0,0,0};
  for (int kc = 0; kc < 2; ++kc) {
    __syncthreads();
    {
      int col = tid >> 1, hh = (tid & 1) * 32;
      const int4* src = (const int4*)&Wt[col*128 + kc*64 + hh];
      int4 a0 = src[0], a1 = src[1], a2 = src[2], a3 = src[3];
      *(int4*)&Ws[col][hh] = a0;      *(int4*)&Ws[col][hh+8] = a1;
      *(int4*)&Ws[col][hh+16] = a2;   *(int4*)&Ws[col][hh+24] = a3;
    }
    __syncthreads();
    #pragma unroll
    for (int ks = 0; ks < 4; ++ks) {
      v4s a = *(const v4s*)&As[rowb + c][kc*64 + ks*16 + g*4];
      #pragma unroll
      for (int ct = 0; ct < 8; ++ct) {
        v4s bf = *(const v4s*)&Ws[ct*16 + c][ks*16 + g*4];
        acc[ct] = mfma16(a, bf, acc[ct]);
      }
    }
  }
  #pragma unroll
  for (int ct = 0; ct < 8; ++ct) {
    int col = ct*16 + c;
    float bb = y ? 0.0f : b1[col];
    #pragma unroll
    for (int r = 0; r < 4; ++r) {
      int row = m0 + rowb + g*4 + r;
      C[(size_t)row*H + col] = f2bf(acc[ct][r] + bb);
    }
  }
}

// ---------------- MFMA chained update v3: 1024 threads / 16 waves,
//   each wave = 16 rows x 32 cols (4 waves/SIMD for latency hiding).
//   + optional fused block-mean + optional fused next-block P/Q --------------
__global__ __launch_bounds__(1024) void k_upd_mfma(
    const float* __restrict__ x, const float* __restrict__ Hagg,
    const short* __restrict__ Wt1,   // [128 col][256 k] bf16
    const float* __restrict__ b1, const float* __restrict__ bvec,
    const float* __restrict__ cntf,
    const short* __restrict__ Wt2,   // [128 col][128 k] bf16
    const float* __restrict__ b2,
    float* __restrict__ xout, float* __restrict__ blocksOut,
    const short* __restrict__ WtN,   // next-block P/Q weights (or null)
    const float* __restrict__ b1N,
    short* __restrict__ Pn, short* __restrict__ Qn)
{
  __shared__ short As[64][264];
  __shared__ short Ws[128][72];
  __shared__ short Us[64][136];
  int tid = threadIdx.x;
  int m0 = blockIdx.x * 64;
  for (int idx = tid; idx < 64*64; idx += 1024) {
    int r = idx >> 6, c4 = idx & 63;
    const float* src = (c4 < 32) ? &x[(size_t)(m0 + r)*H + c4*4]
                                 : &Hagg[(size_t)(m0 + r)*H + (c4-32)*4];
    float4 v = *(const float4*)src;
    short4 s4 = { f2bf(v.x), f2bf(v.y), f2bf(v.z), f2bf(v.w) };
    *(short4*)&As[r][c4*4] = s4;
  }
  int lane = tid & 63, wv = tid >> 6;       // 16 waves
  int c = lane & 15, g = lane >> 4;
  int rowb = (wv & 3) * 16;                 // row group (0..3)
  int cb = (wv >> 2) * 32;                  // col quarter (0..3)
  f32x4 acc[2];
  #pragma unroll
  for (int t = 0; t < 2; ++t) acc[t] = (f32x4){0,0,0,0};
  // GEMM1: K=256 in 4 chunks of 64
  for (int kc = 0; kc < 4; ++kc) {
    __syncthreads();
    {
      int col = tid >> 3, hh = (tid & 7) * 8;
      *(int4*)&Ws[col][hh] = *(const int4*)&Wt1[col*256 + kc*64 + hh];
    }
    __syncthreads();
    #pragma unroll
    for (int ks = 0; ks < 4; ++ks) {
      v4s a = *(const v4s*)&As[rowb + c][kc*64 + ks*16 + g*4];
      #pragma unroll
      for (int ct = 0; ct < 2; ++ct) {
        v4s bf = *(const v4s*)&Ws[cb + ct*16 + c][ks*16 + g*4];
        acc[ct] = mfma16(a, bf, acc[ct]);
      }
    }
  }
  // epilogue 1: U = silu(acc + b1 + bvec*cnt) -> bf16 Us
  {
    float cr[4];
    #pragma unroll
    for (int r = 0; r < 4; ++r) cr[r] = cntf[m0 + rowb + g*4 + r];
    #pragma unroll
    for (int ct = 0; ct < 2; ++ct) {
      int col = cb + ct*16 + c;
      float bb = b1[col], bv = bvec[col];
      #pragma unroll
      for (int r = 0; r < 4; ++r) {
        float v = acc[ct][r] + bb + bv * cr[r];
        Us[rowb + g*4 + r][col] = f2bf(fsilu(v));
        acc[ct][r] = 0.0f;
      }
    }
  }
  // GEMM2: K=128 in 2 chunks of 64 (barrier at loop top covers Us visibility)
  for (int kc = 0; kc < 2; ++kc) {
    __syncthreads();
    {
      int col = tid >> 3, hh = (tid & 7) * 8;
      *(int4*)&Ws[col][hh] = *(const int4*)&Wt2[col*128 + kc*64 + hh];
    }
    __syncthreads();
    #pragma unroll
    for (int ks = 0; ks < 4; ++ks) {
      v4s a = *(const v4s*)&Us[rowb + c][kc*64 + ks*16 + g*4];
      #pragma unroll
      for (int ct = 0; ct < 2; ++ct) {
        v4s bf = *(const v4s*)&Ws[cb + ct*16 + c][ks*16 + g*4];
        acc[ct] = mfma16(a, bf, acc[ct]);
      }
    }
  }
  // final epilogue: xout = acc + b2 + x; optional block-mean; optional stash
  #pragma unroll
  for (int ct = 0; ct < 2; ++ct) {
    int col = cb + ct*16 + c;
    float bb = b2[col];
    float bs = 0.0f;
    #pragma unroll
    for (int r = 0; r < 4; ++r) {
      int row = m0 + rowb + g*4 + r;
      float v = acc[ct][r] + bb + x[(size_t)row*H + col];
      xout[(size_t)row*H + col] = v;
      if (WtN) As[rowb + g*4 + r][col] = f2bf(v);
      bs += v;
    }
    if (blocksOut) {
      bs += __shfl_xor(bs, 16);
      bs += __shfl_xor(bs, 32);
      if (g == 0)
        blocksOut[(size_t)(m0/KATOM + (wv & 3))*H + col] = bs * (1.0f / KATOM);
    }
  }
  // fused next-block P/Q projection from the LDS-resident new-x tile
  if (WtN) {
    __syncthreads();
    for (int y = 0; y < 2; ++y) {
      const short* Wt = WtN + (size_t)y * 128 * 128;
      #pragma unroll
      for (int t2 = 0; t2 < 2; ++t2) acc[t2] = (f32x4){0,0,0,0};
      for (int kc = 0; kc < 2; ++kc) {
        __syncthreads();
        {
          int col = tid >> 3, hh = (tid & 7) * 8;
          *(int4*)&Ws[col][hh] = *(const int4*)&Wt[col*128 + kc*64 + hh];
        }
        __syncthreads();
        #pragma unroll
        for (int ks = 0; ks < 4; ++ks) {
          v4s a = *(const v4s*)&As[rowb + c][kc*64 + ks*16 + g*4];
          #pragma unroll
          for (int ct = 0; ct < 2; ++ct) {
            v4s bf = *(const v4s*)&Ws[cb + ct*16 + c][ks*16 + g*4];
            acc[ct] = mfma16(a, bf, acc[ct]);
          }
        }
      }
      short* C = y ? Qn : Pn;
      #pragma unroll
      for (int ct = 0; ct < 2; ++ct) {
        int col = cb + ct*16 + c;
        float bb = y ? 0.0f : b1N[col];
        #pragma unroll
        for (int r = 0; r < 4; ++r) {
          int row = m0 + rowb + g*4 + r;
          C[(size_t)row*H + col] = f2bf(acc[ct][r] + bb);
        }
      }
    }
  }
}

// ---------------- MFMA block-edge prep: gather+relu -> @edge_w2+b2e ->
//                  @attn_in_w+bin -> Qe/Ke/Ve (bf16 split layout) ------------
__global__ __launch_bounds__(256) void k_eprep_mfma(
    const short* __restrict__ Pb, const short* __restrict__ Qb,
    const int* __restrict__ bedges,
    const short* __restrict__ Wt2e, const float* __restrict__ b2e,
    const short* __restrict__ WtIn, const float* __restrict__ bin,
    short* __restrict__ Qe, short* __restrict__ Ke, short* __restrict__ Ve)
{
  __shared__ short As[64][136];
  __shared__ short Ws[128][72];
  __shared__ short Us[64][136];
  int tid = threadIdx.x;
  int m0 = blockIdx.x * 64;
  for (int idx = tid; idx < 64*32; idx += 256) {
    int r = idx >> 5, c4 = idx & 31;
    int row = m0 + r;
    int g = row >> 9;
    int src = bedges[row*2], dst = bedges[row*2 + 1];
    short4 p4 = *(const short4*)&Pb[(size_t)(g*LBLK + src)*H + c4*4];
    short4 q4 = *(const short4*)&Qb[(size_t)(g*LBLK + dst)*H + c4*4];
    short4 s4;
    s4.x = f2bf(fmaxf(bf2f(p4.x) + bf2f(q4.x), 0.0f));
    s4.y = f2bf(fmaxf(bf2f(p4.y) + bf2f(q4.y), 0.0f));
    s4.z = f2bf(fmaxf(bf2f(p4.z) + bf2f(q4.z), 0.0f));
    s4.w = f2bf(fmaxf(bf2f(p4.w) + bf2f(q4.w), 0.0f));
    *(short4*)&As[r][c4*4] = s4;
  }
  int lane = tid & 63, wv = tid >> 6;
  int c = lane & 15, g = lane >> 4;
  int rowb = wv * 16;
  f32x4 acc[8];
  #pragma unroll
  for (int t = 0; t < 8; ++t) acc[t] = (f32x4){0,0,0,0};
  for (int kc = 0; kc < 2; ++kc) {
    __syncthreads();
    {
      int col = tid >> 1, hh = (tid & 1) * 32;
      const int4* src = (const int4*)&Wt2e[col*128 + kc*64 + hh];
      int4 a0 = src[0], a1 = src[1], a2 = src[2], a3 = src[3];
      *(int4*)&Ws[col][hh] = a0;      *(int4*)&Ws[col][hh+8] = a1;
      *(int4*)&Ws[col][hh+16] = a2;   *(int4*)&Ws[col][hh+24] = a3;
    }
    __syncthreads();
    #pragma unroll
    for (int ks = 0; ks < 4; ++ks) {
      v4s a = *(const v4s*)&As[rowb + c][kc*64 + ks*16 + g*4];
      #pragma unroll
      for (int ct = 0; ct < 8; ++ct) {
        v4s bf = *(const v4s*)&Ws[ct*16 + c][ks*16 + g*4];
        acc[ct] = mfma16(a, bf, acc[ct]);
      }
    }
  }
  #pragma unroll
  for (int ct = 0; ct < 8; ++ct) {
    int col = ct*16 + c;
    float bb = b2e[col];
    #pragma unroll
    for (int r = 0; r < 4; ++r) {
      Us[rowb + g*4 + r][col] = f2bf(acc[ct][r] + bb);
      acc[ct][r] = 0.0f;
    }
  }
  for (int cc = 0; cc < 3; ++cc) {
    for (int kc = 0; kc < 2; ++kc) {
      __syncthreads();
      {
        int col = tid >> 1, hh = (tid & 1) * 32;
        const int4* src = (const int4*)&WtIn[(size_t)(cc*128 + col)*128 + kc*64 + hh];
        int4 a0 = src[0], a1 = src[1], a2 = src[2], a3 = src[3];
        *(int4*)&Ws[col][hh] = a0;      *(int4*)&Ws[col][hh+8] = a1;
        *(int4*)&Ws[col][hh+16] = a2;   *(int4*)&Ws[col][hh+24] = a3;
      }
      __syncthreads();
      #pragma unroll
      for (int ks = 0; ks < 4; ++ks) {
        v4s a = *(const v4s*)&Us[rowb + c][kc*64 + ks*16 + g*4];
        #pragma unroll
        for (int ct = 0; ct < 8; ++ct) {
          v4s bf = *(const v4s*)&Ws[ct*16 + c][ks*16 + g*4];
          acc[ct] = mfma16(a, bf, acc[ct]);
        }
      }
    }
    #pragma unroll
    for (int ct = 0; ct < 8; ++ct) {
      int col = ct*16 + c;
      float bb = bin[cc*128 + col];
      #pragma unroll
      for (int r = 0; r < 4; ++r) {
        int row = m0 + rowb + g*4 + r;
        short val = f2bf(acc[ct][r] + bb);
        if (cc == 0) {
          Qe[(size_t)row*H + col] = val;
        } else {
          // head-major: [graph*8 + h][s][d]
          size_t o = (((size_t)((row >> 9) * NHD + (col >> 4))) * EBE
                      + (row & 511)) * DH + (col & 15);
          ((cc == 1) ? Ke : Ve)[o] = val;
        }
        acc[ct][r] = 0.0f;
      }
    }
  }
}

// ---------------- fused block tail (y-split over qkv chunks) ----------------
__global__ __launch_bounds__(256) void k_bprep(
    const float* __restrict__ bsum, const float* __restrict__ Wout,
    const float* __restrict__ bout, const float* __restrict__ ind,
    const float* __restrict__ blocks,
    const float* __restrict__ Win, const float* __restrict__ bin,
    float* __restrict__ qkv)
{
  __shared__ float As[32][128];
  __shared__ float Ws[16][128];
  __shared__ float Us[32][128];
  int tid = threadIdx.x;
  int m0 = blockIdx.x * 32;
  int chunk = blockIdx.y;
  for (int idx = tid; idx < 32*32; idx += 256) {
    int r = idx >> 5, k4 = idx & 31;
    *(float4*)&As[r][k4*4] = *(const float4*)&bsum[(size_t)(m0 + r)*H + k4*4];
  }
  int rr = tid >> 5;
  int cq = tid & 31;
  float acc[4][4] = {};
  for (int kk0 = 0; kk0 < 128; kk0 += 16) {
    __syncthreads();
    for (int idx = tid; idx < 16*32; idx += 256) {
      int kr = idx >> 5, c4 = idx & 31;
      *(float4*)&Ws[kr][c4*4] = *(const float4*)&Wout[(size_t)(kk0 + kr)*H + c4*4];
    }
    __syncthreads();
    #pragma unroll
    for (int k4 = 0; k4 < 4; ++k4) {
      float4 w0 = *(const float4*)&Ws[k4*4+0][cq*4];
      float4 w1 = *(const float4*)&Ws[k4*4+1][cq*4];
      float4 w2 = *(const float4*)&Ws[k4*4+2][cq*4];
      float4 w3 = *(const float4*)&Ws[k4*4+3][cq*4];
      #pragma unroll
      for (int i = 0; i < 4; ++i) {
        float4 a = *(const float4*)&As[rr + 8*i][kk0 + k4*4];
        acc[i][0] += a.x*w0.x + a.y*w1.x + a.z*w2.x + a.w*w3.x;
        acc[i][1] += a.x*w0.y + a.y*w1.y + a.z*w2.y + a.w*w3.y;
        acc[i][2] += a.x*w0.z + a.y*w1.z + a.z*w2.z + a.w*w3.z;
        acc[i][3] += a.x*w0.w + a.y*w1.w + a.z*w2.w + a.w*w3.w;
      }
    }
  }
  #pragma unroll
  for (int i = 0; i < 4; ++i) {
    int m = m0 + rr + 8*i;
    float bs = ind[m];
    float4 u;
    float* pu = &u.x;
    #pragma unroll
    for (int j = 0; j < 4; ++j) {
      int c = cq*4 + j;
      pu[j] = acc[i][j] + bout[c] * bs + blocks[(size_t)m*H + c];
    }
    *(float4*)&Us[rr + 8*i][cq*4] = u;
    acc[i][0] = 0.0f; acc[i][1] = 0.0f; acc[i][2] = 0.0f; acc[i][3] = 0.0f;
  }
  for (int kk0 = 0; kk0 < 128; kk0 += 16) {
    __syncthreads();
    for (int idx = tid; idx < 16*32; idx += 256) {
      int kr = idx >> 5, c4 = idx & 31;
      *(float4*)&Ws[kr][c4*4] =
          *(const float4*)&Win[(size_t)(kk0 + kr)*384 + chunk*128 + c4*4];
    }
    __syncthreads();
    #pragma unroll
    for (int k4 = 0; k4 < 4; ++k4) {
      float4 w0 = *(const float4*)&Ws[k4*4+0][cq*4];
      float4 w1 = *(const float4*)&Ws[k4*4+1][cq*4];
      float4 w2 = *(const float4*)&Ws[k4*4+2][cq*4];
      float4 w3 = *(const float4*)&Ws[k4*4+3][cq*4];
      #pragma unroll
      for (int i = 0; i < 4; ++i) {
        float4 a = *(const float4*)&Us[rr + 8*i][kk0 + k4*4];
        acc[i][0] += a.x*w0.x + a.y*w1.x + a.z*w2.x + a.w*w3.x;
        acc[i][1] += a.x*w0.y + a.y*w1.y + a.z*w2.y + a.w*w3.y;
        acc[i][2] += a.x*w0.z + a.y*w1.z + a.z*w2.z + a.w*w3.z;
        acc[i][3] += a.x*w0.w + a.y*w1.w + a.z*w2.w + a.w*w3.w;
      }
    }
  }
  #pragma unroll
  for (int i = 0; i < 4; ++i) {
    int m = m0 + rr + 8*i;
    float4 out;
    float* po = &out.x;
    #pragma unroll
    for (int j = 0; j < 4; ++j)
      po[j] = acc[i][j] + bin[chunk*128 + cq*4 + j];
    *(float4*)&qkv[(size_t)m*384 + chunk*128 + cq*4] = out;
  }
}

// ---------------- MFMA bf16 flash attention (split bf16 Qe/Ke/Ve) -----------
__global__ __launch_bounds__(256) void k_eattn(
    const short* __restrict__ Qe, const short* __restrict__ Ke,
    const short* __restrict__ Ve, float* __restrict__ ea)
{
  constexpr int S = EBE;
  constexpr int NR = BSG * NHD * S;
  __shared__ short Ks[S * DH];
  __shared__ short Vt[DH * (S + 4)];
  int rb = blockIdx.x & 3;
  int bh = blockIdx.x >> 2;
  int b = bh >> 3, h = bh & 7;
  int tid = threadIdx.x;
  const short* kb = Ke + (size_t)bh * S * DH;
  const short* vb = Ve + (size_t)bh * S * DH;
  for (int t = tid; t < S * DH / 8; t += 256)
    ((int4*)Ks)[t] = ((const int4*)kb)[t];
  for (int t = tid; t < S * 2; t += 256) {
    int j = t >> 1, half = t & 1;
    int4 v8 = ((const int4*)vb)[t];
    short vs[8]; *(int4*)vs = v8;
    #pragma unroll
    for (int k = 0; k < 8; ++k)
      Vt[(half*8 + k) * (S + 4) + j] = vs[k];
  }
  __syncthreads();
  int lane = tid & 63, wv = tid >> 6;
  int q = lane & 15;
  int g = lane >> 4;
  for (int qs = 0; qs < 2; ++qs) {
    int row = rb * 128 + qs * 64 + wv * 16 + q;
    v4s qf = *(const v4s*)&Qe[((size_t)b * S + row) * H + h * DH + g * 4];
    f32x4 zero = {0.f, 0.f, 0.f, 0.f};
    f32x4 o = zero;
    float m = -1e30f, lsum = 0.0f;
    for (int t = 0; t < S / 16; ++t) {
      v4s ak = *(const v4s*)&Ks[(t * 16 + q) * DH + g * 4];
      f32x4 st = mfma16(ak, qf, zero);
      float tm = fmaxf(fmaxf(st[0], st[1]), fmaxf(st[2], st[3]));
      tm = fmaxf(tm, __shfl_xor(tm, 16));
      tm = fmaxf(tm, __shfl_xor(tm, 32));
      float mn = fmaxf(m, tm);
      float corr = __expf((m - mn) * 0.25f);
      m = mn;
      float p0 = __expf((st[0] - mn) * 0.25f);
      float p1 = __expf((st[1] - mn) * 0.25f);
      float p2 = __expf((st[2] - mn) * 0.25f);
      float p3 = __expf((st[3] - mn) * 0.25f);
      lsum = lsum * corr + ((p0 + p1) + (p2 + p3));
      o[0] *= corr; o[1] *= corr; o[2] *= corr; o[3] *= corr;
      v4s pb = { f2bf(p0), f2bf(p1), f2bf(p2), f2bf(p3) };
      v4s av = *(const v4s*)&Vt[q * (S + 4) + t * 16 + g * 4];
      o = mfma16(av, pb, o);
    }
    float lt = lsum + __shfl_xor(lsum, 16);
    lt += __shfl_xor(lt, 32);
    float inv = 1.0f / lt;
    float4 outv = { o[0]*inv, o[1]*inv, o[2]*inv, o[3]*inv };
    ((float4*)ea)[(size_t)g * NR + (size_t)bh * S + row] = outv;
  }
}

// gather ea rows per (block, channel) via block-edge CSR; divide by cnt
__global__ __launch_bounds__(256) void k_bsum_gather(
    const float* __restrict__ ea, const int* __restrict__ blist,
    const int* __restrict__ boff, float* __restrict__ bsum)
{
  constexpr int NR = BSG * NHD * EBE;
  int idx = blockIdx.x * 256 + threadIdx.x;
  int i = idx >> 5, c4 = idx & 31;
  int b = i >> 6, blk = i & 63;
  int h = c4 >> 2, d4 = c4 & 3;
  int e0 = boff[b*65 + blk], e1 = boff[b*65 + blk + 1];
  const float4* ea4 = (const float4*)ea;
  size_t basein = (size_t)d4 * NR + (size_t)(b*NHD + h) * EBE;
  float4 s = {0, 0, 0, 0};
  for (int e = e0; e < e1; ++e) {
    int srow = blist[b*EBE + e];
    float4 v = ea4[basein + srow];
    s.x += v.x; s.y += v.y; s.z += v.z; s.w += v.w;
  }
  float cnt = (float)(e1 - e0);
  float sc = (cnt > 0.0f) ? (1.0f / cnt) : 0.0f;
  float4 o = {s.x*sc, s.y*sc, s.z*sc, s.w*sc};
  *(float4*)&bsum[(size_t)i*H + c4*4] = o;
}

// ---------------- block self-attention v2: one block per (graph, head) ------
__global__ __launch_bounds__(64) void k_attnS(
    const float* __restrict__ qkv, float* __restrict__ m2)
{
  __shared__ float Ks[LBLK][DH];
  __shared__ float Vs[LBLK][DH];
  __shared__ float red[LBLK][DH + 1];
  int b = blockIdx.x >> 3, h = blockIdx.x & 7;
  int tid = threadIdx.x;
  const float* base = qkv + (size_t)b * LBLK * 384;
  for (int t = tid; t < 256; t += 64) {
    int j = t >> 2, d4 = t & 3;
    *(float4*)&Ks[j][d4*4] = *(const float4*)(base + (size_t)j*384 + 128 + h*DH + d4*4);
    *(float4*)&Vs[j][d4*4] = *(const float4*)(base + (size_t)j*384 + 256 + h*DH + d4*4);
  }
  __syncthreads();
  int s = tid;
  const float4* qp = (const float4*)(base + (size_t)s * 384 + h * DH);
  float4 q0 = qp[0], q1 = qp[1], q2 = qp[2], q3 = qp[3];
  float m = -1e30f, l = 0.0f;
  float4 o0 = {0,0,0,0}, o1 = {0,0,0,0}, o2 = {0,0,0,0}, o3 = {0,0,0,0};
  for (int c0 = 0; c0 < LBLK; c0 += 32) {
    float scv[32];
    float mc = -1e30f;
    #pragma unroll
    for (int j = 0; j < 32; ++j) {
      float4 k0 = *(const float4*)&Ks[c0+j][0];
      float4 k1 = *(const float4*)&Ks[c0+j][4];
      float4 k2 = *(const float4*)&Ks[c0+j][8];
      float4 k3 = *(const float4*)&Ks[c0+j][12];
      float s0 = q0.x*k0.x + q0.y*k0.y + q0.z*k0.z + q0.w*k0.w;
      float s1 = q1.x*k1.x + q1.y*k1.y + q1.z*k1.z + q1.w*k1.w;
      float s2 = q2.x*k2.x + q2.y*k2.y + q2.z*k2.z + q2.w*k2.w;
      float s3 = q3.x*k3.x + q3.y*k3.y + q3.z*k3.z + q3.w*k3.w;
      float sc = (s0 + s1) + (s2 + s3);
      scv[j] = sc;
      mc = fmaxf(mc, sc);
    }
    float mn = fmaxf(m, mc);
    float corr = __expf((m - mn) * 0.25f);
    l *= corr;
    o0.x *= corr; o0.y *= corr; o0.z *= corr; o0.w *= corr;
    o1.x *= corr; o1.y *= corr; o1.z *= corr; o1.w *= corr;
    o2.x *= corr; o2.y *= corr; o2.z *= corr; o2.w *= corr;
    o3.x *= corr; o3.y *= corr; o3.z *= corr; o3.w *= corr;
    m = mn;
    #pragma unroll
    for (int j = 0; j < 32; ++j) {
      float p = __expf((scv[j] - m) * 0.25f);
      l += p;
      float4 v0 = *(const float4*)&Vs[c0+j][0];
      float4 v1 = *(const float4*)&Vs[c0+j][4];
      float4 v2 = *(const float4*)&Vs[c0+j][8];
      float4 v3 = *(const float4*)&Vs[c0+j][12];
      o0.x += p*v0.x; o0.y += p*v0.y; o0.z += p*v0.z; o0.w += p*v0.w;
      o1.x += p*v1.x; o1.y += p*v1.y; o1.z += p*v1.z; o1.w += p*v1.w;
      o2.x += p*v2.x; o2.y += p*v2.y; o2.z += p*v2.z; o2.w += p*v2.w;
      o3.x += p*v3.x; o3.y += p*v3.y; o3.z += p*v3.z; o3.w += p*v3.w;
    }
  }
  float inv = (1.0f / l) * (1.0f / 64.0f);
  float ov[DH] = {o0.x,o0.y,o0.z,o0.w, o1.x,o1.y,o1.z,o1.w,
                  o2.x,o2.y,o2.z,o2.w, o3.x,o3.y,o3.z,o3.w};
  #pragma unroll
  for (int d = 0; d < DH; ++d) red[s][d] = ov[d] * inv;
  __syncthreads();
  if (s < DH) {
    float acc = 0.0f;
    for (int r = 0; r < LBLK; ++r) acc += red[r][s];
    m2[(size_t)b * H + h * DH + s] = acc;
  }
}

// ---------------- final: out-proj + LN + 3-layer MLP ----------------
__device__ __forceinline__ float bsum128(float v, float* red) {
  int t = threadIdx.x;
  red[t] = v; __syncthreads();
  #pragma unroll
  for (int off = 64; off > 0; off >>= 1) {
    if (t < off) red[t] += red[t + off];
    __syncthreads();
  }
  float s = red[0];
  __syncthreads();
  return s;
}

__global__ __launch_bounds__(128) void k_final(
    const float* __restrict__ m2, const float* __restrict__ out_w,
    const float* __restrict__ out_b, const float* __restrict__ lng,
    const float* __restrict__ lnb, const float* __restrict__ w1,
    const float* __restrict__ b1, const float* __restrict__ w2,
    const float* __restrict__ b2, const float* __restrict__ w3,
    const float* __restrict__ b3, float* __restrict__ out)
{
  __shared__ float buf[128];
  __shared__ float red[128];
  int b = blockIdx.x, t = threadIdx.x;
  buf[t] = m2[b*H + t];
  __syncthreads();
  float g = out_b[t];
  for (int k = 0; k < H; ++k) g += buf[k] * out_w[k*H + t];
  float mu = bsum128(g, red) * (1.0f / H);
  float df = g - mu;
  float var = bsum128(df * df, red) * (1.0f / H);
  float gn = df / sqrtf(var + 1e-5f) * lng[t] + lnb[t];
  __syncthreads();
  buf[t] = gn; __syncthreads();
  float h1 = b1[t];
  for (int k = 0; k < H; ++k) h1 += buf[k] * w1[k*H + t];
  h1 = fmaxf(h1, 0.0f);
  __syncthreads();
  buf[t] = h1; __syncthreads();
  float h2 = b2[t];
  for (int k = 0; k < H; ++k) h2 += buf[k] * w2[k*H + t];
  h2 = fmaxf(h2, 0.0f);
  float tot = bsum128(h2 * w3[t], red);
  if (t == 0) out[b] = tot + b3[0];
}

extern "C" void kernel_launch(void* const* d_in, const int* in_sizes, int n_in,
                              void* d_out, int out_size, void* d_ws, size_t ws_size,
                              hipStream_t stream) {
  (void)in_sizes; (void)n_in; (void)out_size; (void)ws_size;
  const int*   A          = (const int*)d_in[0];
  const int*   apos       = (const int*)d_in[1];
  const int*   btypes     = (const int*)d_in[2];
  const float* coords     = (const float*)d_in[3];
  const int*   edge_index = (const int*)d_in[4];
  const int*   bedges     = (const int*)d_in[5];
  const float* emb_atom   = (const float*)d_in[6];
  const float* emb_pos    = (const float*)d_in[7];
  const float* emb_block  = (const float*)d_in[8];
  const float* rbf_freq   = (const float*)d_in[9];
  const float* inter_w1   = (const float*)d_in[10];
  const float* inter_b1   = (const float*)d_in[11];
  const float* inter_w2   = (const float*)d_in[12];
  const float* inter_b2   = (const float*)d_in[13];
  const float* upd_w1     = (const float*)d_in[14];
  const float* upd_b1     = (const float*)d_in[15];
  const float* upd_w2     = (const float*)d_in[16];
  const float* upd_b2     = (const float*)d_in[17];
  const float* edge_w1    = (const float*)d_in[18];
  const float* edge_b1    = (const float*)d_in[19];
  const float* edge_w2    = (const float*)d_in[20];
  const float* edge_b2    = (const float*)d_in[21];
  const float* attn_in_w  = (const float*)d_in[22];
  const float* attn_in_b  = (const float*)d_in[23];
  const float* attn_out_w = (const float*)d_in[24];
  const float* attn_out_b = (const float*)d_in[25];
  const float* ln_g       = (const float*)d_in[26];
  const float* ln_b       = (const float*)d_in[27];
  const float* fin_w1     = (const float*)d_in[28];
  const float* fin_b1     = (const float*)d_in[29];
  const float* fin_w2     = (const float*)d_in[30];
  const float* fin_b2     = (const float*)d_in[31];
  const float* fin_w3     = (const float*)d_in[32];
  const float* fin_b3     = (const float*)d_in[33];
  float* out = (float*)d_out;

  float* ws = (float*)d_ws;
  float* x      = ws + 0;
  short* P      = (short*)(ws + 2097152);   // NA*H bf16
  short* Q      = (short*)(ws + 4194304);   // NA*H bf16
  float* Hagg   = ws + 6291456;
  float* rbf_s  = ws + 8388608;    // E*6 (sorted RBF)
  float* cntf   = ws + 9961472;    // NA
  float* blocks = ws + 9977856;    // NBLKT*H
  short* Pb     = (short*)(ws + 10108928);  // NBLKT*H bf16
  short* Qb     = (short*)(ws + 10240000);  // NBLKT*H bf16
  // edge-attention split buffers (bf16) + block-level qkv (f32):
  short* Qe     = (short*)(ws + 12468224);            // 16*512*128 bf16
  short* Ke     = (short*)(ws + 12468224 + 524288);   // 16*8*512*16 bf16
  short* Ve     = (short*)(ws + 12468224 + 1048576);  // 16*8*512*16 bf16
  float* qkvB   = ws + 12468224 + 1572864;            // NBLKT*384 f32
  float* bsum   = ws + 15613952;   // NBLKT*H
  float* ind    = ws + 15746048;   // NBLKT
  float* m2     = ws + 15747072;   // BSG*H
  int* blist    = (int*)(ws + 15749120);  // BSG*EBE ints
  int* boff     = (int*)(ws + 15757312);  // BSG*65 ints
  // sort scratch lives in the old-Epre region (dead until attention):
  int* ej_s   = (int*)(ws + 10371072);          // NE ints
  int* off    = (int*)(ws + 10371072 + 262144); // NA+1 ints
  int* cur    = (int*)(ws + 10371072 + 278784); // NA ints
  int* cnt    = (int*)(ws + 10371072 + 295168); // NA ints
  float* bvec = ws + 10371072 + 311552;         // 2 x 128 floats
  // bf16 transposed weights: high region
  short* wt_pq = (short*)(ws + 16777216);            // 2*2*128*128
  short* wt_u1 = (short*)(ws + 16777216 + 32768);    // 2*128*256
  short* wt_u2 = (short*)(ws + 16777216 + 65536);    // 2*128*128
  short* wt_e1 = (short*)(ws + 16777216 + 81920);    // 2*128*128
  short* wt_e2 = (short*)(ws + 16777216 + 98304);    // 128*128
  short* wt_in = (short*)(ws + 16777216 + 106496);   // 384*128
  // edge-attention output (written after sort scratch is dead):
  float* ea     = ws + 10371072;   // 65536*16 floats (old Epre region)

  const int* ei = edge_index;
  const int* ej = edge_index + NE;

  // ---- edge sort (once; reused by both interaction blocks) ----
  (void)hipMemsetAsync(cnt, 0, NA * sizeof(int), stream);
  k_hist<<<NE/256, 256, 0, stream>>>(ei, cnt);
  k_scan<<<1, 1024, 0, stream>>>(cnt, off, cur, cntf);
  // merged: edge scatter+RBF + block-edge CSR
  k_scatter_b<<<NE/256 + BSG, 256, 0, stream>>>(ei, ej, coords, rbf_freq, cur,
                                                ej_s, rbf_s,
                                                bedges, blist, boff, ind);
  // merged weight prep: wprep + all bf16 col-major conversions
  k_prep<<<384, 256, 0, stream>>>(inter_w2, upd_w1, inter_b2, bvec, wt_u1,
                                  inter_w1, upd_w2, edge_w1, edge_w2, attn_in_w,
                                  wt_pq, wt_u2, wt_e1, wt_e2, wt_in);

  // ---- interaction block 0 ----
  k_embed_pq<<<dim3(NA/64, 2), 256, 0, stream>>>(
      A, apos, btypes, emb_atom, emb_pos, emb_block,
      wt_pq, inter_b1, x, P, Q);
  k_edge_csr<<<NA/4, 256, 0, stream>>>(P, Q, rbf_s,
                                       inter_w1 + 256*H, ej_s, off, Hagg);
  // chained update (1024 thr, 16 waves) + fused next-block P/Q projection
  k_upd_mfma<<<NA/64, 1024, 0, stream>>>(
      x, Hagg, wt_u1, upd_b1, bvec, cntf, wt_u2, upd_b2, x, nullptr,
      wt_pq + (size_t)1*2*128*128, inter_b1 + H, P, Q);

  // ---- interaction block 1 ----
  k_edge_csr<<<NA/4, 256, 0, stream>>>(P, Q, rbf_s,
                                       inter_w1 + (size_t)262*H + 256*H,
                                       ej_s, off, Hagg);
  // chained update (1024 thr) + fused block-mean
  k_upd_mfma<<<NA/64, 1024, 0, stream>>>(
      x, Hagg, wt_u1 + (size_t)128*256, upd_b1 + H, bvec + H, cntf,
      wt_u2 + (size_t)128*128, upd_b2 + H, x, blocks,
      nullptr, nullptr, nullptr, nullptr);

  // MFMA: Pb = blocks@edge_w1a + b (y=0) ; Qb = blocks@edge_w1b (y=1), bf16 out
  k_pq_mfma<<<dim3(NBLKT/64, 2), 256, 0, stream>>>(blocks, wt_e1, edge_b1, Pb, Qb);
  // MFMA: gather+relu -> @edge_w2+b -> @attn_in_w+b -> Qe/Ke/Ve (bf16 split)
  k_eprep_mfma<<<BSG*EBE/64, 256, 0, stream>>>(Pb, Qb, bedges, wt_e2, edge_b2,
                                               wt_in, attn_in_b, Qe, Ke, Ve);
  // MFMA bf16 flash attention (coalesced bf16 staging)
  k_eattn<<<BSG*NHD*(EBE/128), 256, 0, stream>>>(Qe, Ke, Ve, ea);
  k_bsum_gather<<<NBLKT*32/256, 256, 0, stream>>>(ea, blist, boff, bsum);
  // fused tail (y-split, 96 workgroups)
  k_bprep<<<dim3(NBLKT/32, 3), 256, 0, stream>>>(bsum, attn_out_w, attn_out_b,
                                                 ind, blocks, attn_in_w,
                                                 attn_in_b, qkvB);
  // block self-attention: one block per (graph, head), 128 workgroups
  k_attnS<<<BSG*NHD, 64, 0, stream>>>(qkvB, m2);
  k_final<<<BSG, 128, 0, stream>>>(m2, attn_out_w, attn_out_b, ln_g, ln_b,
                                   fin_w1, fin_b1, fin_w2, fin_b2, fin_w3, fin_b3, out);
}